// Round 1
// baseline (1027.769 us; speedup 1.0000x reference)
//
#include <hip/hip_runtime.h>
#include <stdint.h>

// BiRNN on MI355X.
// Key facts exploited:
//  - out[:, -1] only => backward LSTM needs exactly ONE step from zero state.
//  - forward recurrence is independent per batch row => persistent kernel,
//    32 blocks x 512 threads, NB=16 batch rows/block, zero inter-block sync.
//  - W_hh (bf16, 512 KB) kept CU-resident: 46/64 A-frags per wave in VGPRs,
//    18/64 in LDS (144 KB) -- streaming from L2 would cost ~660us (64 B/cy/CU).
//  - all matmuls via mfma_f32_16x16x32_bf16, fp32 accum; xg stored bf16 in ws.

typedef unsigned short u16;
typedef __bf16 bf16x8 __attribute__((ext_vector_type(8)));
typedef float  f32x4  __attribute__((ext_vector_type(4)));

#define B_    512
#define L_    200
#define EMB_  128
#define TDIM_ 10
#define IN_   138
#define INP_  160   // feat padded K (5 x 32)
#define H_    256
#define G4_   1024
#define T_    200

static __device__ __forceinline__ float bf2f(u16 u) {
  union { uint32_t i; float f; } v; v.i = ((uint32_t)u) << 16; return v.f;
}
static __device__ __forceinline__ u16 f2bf(float f) {
  __bf16 h = (__bf16)f; return __builtin_bit_cast(u16, h);
}
static __device__ __forceinline__ float bflo(uint32_t u) {
  return __builtin_bit_cast(float, (uint32_t)(u << 16));
}
static __device__ __forceinline__ float bfhi(uint32_t u) {
  return __builtin_bit_cast(float, (uint32_t)(u & 0xffff0000u));
}
static __device__ __forceinline__ float sigf(float x) {
  return __builtin_amdgcn_rcpf(1.0f + __expf(-x));
}
static __device__ __forceinline__ float tanh_(float x) {
  x = fminf(fmaxf(x, -15.f), 15.f);
  float e = __expf(2.0f * x);
  return (e - 1.0f) * __builtin_amdgcn_rcpf(e + 1.0f);
}
static __device__ __forceinline__ f32x4 mfma16(bf16x8 a, bf16x8 b, f32x4 c) {
  return __builtin_amdgcn_mfma_f32_16x16x32_bf16(a, b, c, 0, 0, 0);
}
static __device__ __forceinline__ f32x4 vzero4() {
  f32x4 v; v[0] = 0.f; v[1] = 0.f; v[2] = 0.f; v[3] = 0.f; return v;
}

// ---------------- K1: s[b] = sum_l t^2 ----------------
__global__ void k_norm(const int* __restrict__ x, float* __restrict__ s) {
  int b = blockIdx.x;
  int tid = threadIdx.x;
  float v = 0.f;
  if (tid < L_) {
    float t = (float)x[(b * L_ + tid) * 2];
    v = t * t;
  }
  #pragma unroll
  for (int o = 32; o; o >>= 1) v += __shfl_down(v, o);
  __shared__ float p[4];
  if ((tid & 63) == 0) p[tid >> 6] = v;
  __syncthreads();
  if (tid == 0) s[b] = p[0] + p[1] + p[2] + p[3];
}

// ---------------- K0b: W_hh fp32 -> frag-ordered bf16 ----------------
// layout: frag id fid = (w*8+tt)*8+kp ; element (fid*64 + lane)*8 + j
// A-frag: lane=(q<<4)|mm holds A[g=(w+8*tt)*16+mm][k=kp*32+q*8+j]
__global__ void k_prep_whh(const float* __restrict__ whh, u16* __restrict__ wfrag) {
  int idx = blockIdx.x * blockDim.x + threadIdx.x;  // < 262144
  int j = idx & 7;
  int lane = (idx >> 3) & 63;
  int fid = idx >> 9;
  int kp = fid & 7, tt = (fid >> 3) & 7, w = fid >> 6;
  int mm = lane & 15, q = lane >> 4;
  int g = (w + 8 * tt) * 16 + mm;
  int k = kp * 32 + q * 8 + j;
  wfrag[idx] = f2bf(whh[g * 256 + k]);
}

// ---------------- K2: features (t_emb normalized | l_emb | pad) bf16 ----------------
__global__ void k_feat(const int* __restrict__ x, const float* __restrict__ emb,
                       const float* __restrict__ tsW, const float* __restrict__ s,
                       u16* __restrict__ feat) {
  int idx = blockIdx.x * blockDim.x + threadIdx.x;
  if (idx >= B_ * L_ * INP_) return;
  int c = idx % INP_;
  int row = idx / INP_;
  int b = row / L_;
  float v = 0.f;
  if (c < TDIM_) {
    float t = (float)x[row * 2 + 0];
    float wd = tsW[c];
    float den = fmaxf(fabsf(wd) * sqrtf(s[b]), 1e-12f);
    v = t * wd / den;
  } else if (c < IN_) {
    int id = x[row * 2 + 1];
    int idc = id < 0 ? 0 : id;
    float e = emb[(long)idc * EMB_ + (c - TDIM_)];
    v = (id >= 0) ? e : 0.f;
  }
  feat[idx] = f2bf(v);
}

// ---------------- K3: xg = feat @ W_ih^T + b_ih + b_hh  (bf16 out) ----------------
// M-tile 128, N-tile 64; W tile staged in LDS (stride 168 to dodge bank conflicts)
__global__ __launch_bounds__(256) void k_xg(
    const u16* __restrict__ feat, const float* __restrict__ wih,
    const float* __restrict__ bih, const float* __restrict__ bhh,
    u16* __restrict__ xg) {
  __shared__ u16 Bs[64 * 168];
  const int nt = blockIdx.x;   // 0..15
  const int mt = blockIdx.y;   // 0..799
  const int tid = threadIdx.x;
  const int w = tid >> 6, lane = tid & 63;
  const int q = lane >> 4, nm = lane & 15;
  for (int i = tid; i < 64 * 168; i += 256) {
    int gl = i / 168, f = i % 168;
    float v = (f < IN_) ? wih[(nt * 64 + gl) * IN_ + f] : 0.f;
    Bs[gl * 168 + f] = f2bf(v);
  }
  __syncthreads();
  f32x4 acc[2][4];
  #pragma unroll
  for (int m = 0; m < 2; ++m)
    #pragma unroll
    for (int nu = 0; nu < 4; ++nu) acc[m][nu] = vzero4();
  const u16* arow = feat + (long)(mt * 128 + w * 32) * INP_;
  #pragma unroll
  for (int kp = 0; kp < 5; ++kp) {
    bf16x8 a0 = *(const bf16x8*)(arow + (nm * INP_ + kp * 32 + q * 8));
    bf16x8 a1 = *(const bf16x8*)(arow + ((16 + nm) * INP_ + kp * 32 + q * 8));
    #pragma unroll
    for (int nu = 0; nu < 4; ++nu) {
      bf16x8 bb = *(const bf16x8*)&Bs[(nu * 16 + nm) * 168 + kp * 32 + q * 8];
      acc[0][nu] = mfma16(a0, bb, acc[0][nu]);
      acc[1][nu] = mfma16(a1, bb, acc[1][nu]);
    }
  }
  #pragma unroll
  for (int nu = 0; nu < 4; ++nu) {
    int g = nt * 64 + nu * 16 + nm;
    float bias = bih[g] + bhh[g];
    #pragma unroll
    for (int m = 0; m < 2; ++m) {
      long row = mt * 128 + w * 32 + m * 16 + 4 * q;
      #pragma unroll
      for (int r = 0; r < 4; ++r)
        xg[(row + r) * G4_ + g] = f2bf(acc[m][nu][r] + bias);
    }
  }
}

// ---------------- K4: forward LSTM scan, weight-resident persistent kernel ----------------
// 32 blocks x 512 thr (8 waves, 2 waves/SIMD). Block bi owns batch rows [16*bi,16*bi+16).
// Wave w owns m-tiles {w+8*tt}: tt in {0,1}=i, {2,3}=f, {4,5}=g, {6,7}=o gates,
// so each lane holds matching i/f/g/o accum elements -> c/h update is lane-local.
__global__ __launch_bounds__(512, 2) void k_lstm_f(
    const u16* __restrict__ wfrag, const u16* __restrict__ xg,
    float* __restrict__ hf) {
  __shared__ uint4 ldsW[18 * 8 * 64];  // 147456 B: LDS-resident W frags
  __shared__ u16 hls[16 * 264];        // 8448 B: h[b][k] bf16, padded stride 264
  const int tid = threadIdx.x;
  const int w = tid >> 6;
  const int lane = tid & 63;
  const int q = lane >> 4;
  const int nn = lane & 15;
  const int b = blockIdx.x * 16 + nn;

  // load weight frags: 46 -> VGPR, 18 -> LDS (per wave)
  const uint4* wf4 = (const uint4*)wfrag;
  bf16x8 wv[46];
  #pragma unroll
  for (int tt = 0; tt < 8; ++tt) {
    #pragma unroll
    for (int kp = 0; kp < 8; ++kp) {
      uint4 u = wf4[(long)((w * 8 + tt) * 8 + kp) * 64 + lane];
      if (kp >= 6 || (kp == 5 && tt >= 6)) {
        int li = (kp == 5) ? (tt - 6) : ((kp == 6) ? (2 + tt) : (10 + tt));
        ldsW[(w * 18 + li) * 64 + lane] = u;
      } else {
        int vi = (kp <= 4) ? (tt * 5 + kp) : (40 + tt);
        wv[vi] = __builtin_bit_cast(bf16x8, u);
      }
    }
  }
  for (int i = tid; i < 16 * 264; i += 512) hls[i] = 0;

  const u16* xgb = xg + (long)b * L_ * G4_;
  uint2 pf[8];
  #pragma unroll
  for (int tt = 0; tt < 8; ++tt) {
    int g = (w + 8 * tt) * 16 + 4 * q;
    pf[tt] = *(const uint2*)(xgb + g);  // t = 0
  }
  f32x4 cst[2];
  cst[0] = vzero4();
  cst[1] = vzero4();
  __syncthreads();

  for (int t = 0; t < T_; ++t) {
    // init accumulators with xg (covers the "+xg_t" term for free)
    f32x4 acc[8];
    #pragma unroll
    for (int tt = 0; tt < 8; ++tt) {
      acc[tt][0] = bflo(pf[tt].x);
      acc[tt][1] = bfhi(pf[tt].x);
      acc[tt][2] = bflo(pf[tt].y);
      acc[tt][3] = bfhi(pf[tt].y);
    }
    // g_pre += W_hh . h
    #pragma unroll
    for (int kp = 0; kp < 8; ++kp) {
      bf16x8 bh = *(const bf16x8*)&hls[nn * 264 + kp * 32 + q * 8];
      #pragma unroll
      for (int tt = 0; tt < 8; ++tt) {
        bf16x8 a;
        if (kp >= 6 || (kp == 5 && tt >= 6)) {
          int li = (kp == 5) ? (tt - 6) : ((kp == 6) ? (2 + tt) : (10 + tt));
          a = __builtin_bit_cast(bf16x8, ldsW[(w * 18 + li) * 64 + lane]);
        } else {
          int vi = (kp <= 4) ? (tt * 5 + kp) : (40 + tt);
          a = wv[vi];
        }
        acc[tt] = mfma16(a, bh, acc[tt]);
      }
    }
    // prefetch next step's xg (latency hidden by epilogue + barriers)
    const int tn = (t + 1 < T_) ? (t + 1) : (T_ - 1);
    #pragma unroll
    for (int tt = 0; tt < 8; ++tt) {
      int g = (w + 8 * tt) * 16 + 4 * q;
      pf[tt] = *(const uint2*)(xgb + (long)tn * G4_ + g);
    }
    __syncthreads();  // all hls reads done
    #pragma unroll
    for (int j = 0; j < 2; ++j) {
      uint32_t p0 = 0, p1 = 0;
      f32x4 hv;
      #pragma unroll
      for (int r = 0; r < 4; ++r) {
        float iv = acc[0 + j][r];
        float fv = acc[2 + j][r];
        float gv = acc[4 + j][r];
        float ov = acc[6 + j][r];
        float c = sigf(fv) * cst[j][r] + sigf(iv) * tanh_(gv);
        float h = sigf(ov) * tanh_(c);
        cst[j][r] = c;
        hv[r] = h;
        uint32_t hb16 = f2bf(h);
        if (r == 0) p0 = hb16;
        else if (r == 1) p0 |= hb16 << 16;
        else if (r == 2) p1 = hb16;
        else p1 |= hb16 << 16;
      }
      uint2 pk; pk.x = p0; pk.y = p1;
      *(uint2*)&hls[nn * 264 + (16 * w + 128 * j + 4 * q)] = pk;
      if (t == T_ - 1) {
        *(f32x4*)&hf[(long)b * H_ + 16 * w + 128 * j + 4 * q] = hv;
      }
    }
    __syncthreads();  // hls ready for next step
  }
}

// ---------------- K5: backward LSTM = ONE step from zero state at l=L-1 ----------------
__global__ __launch_bounds__(256) void k_bwd(
    const u16* __restrict__ feat, const float* __restrict__ wih,
    const float* __restrict__ bih, const float* __restrict__ bhh,
    float* __restrict__ hb) {
  int b = blockIdx.x;
  int tid = threadIdx.x;
  __shared__ float fv[IN_];
  if (tid < IN_) fv[tid] = bf2f(feat[((long)b * L_ + (L_ - 1)) * INP_ + tid]);
  __syncthreads();
  float g4[4];
  #pragma unroll
  for (int gg = 0; gg < 4; ++gg) {
    int g = gg * H_ + tid;
    float acc = bih[g] + bhh[g];
    const float* wr = wih + (long)g * IN_;
    #pragma unroll 2
    for (int f = 0; f < IN_; ++f) acc += wr[f] * fv[f];
    g4[gg] = acc;
  }
  float c = sigf(g4[0]) * tanh_(g4[2]);   // sig(f)*c0 term is zero (c0 = 0)
  float h = sigf(g4[3]) * tanh_(c);
  hb[b * H_ + tid] = h;
}

// ---------------- K6: fc head ----------------
__global__ void k_fc(const float* __restrict__ hf, const float* __restrict__ hb,
                     const float* __restrict__ fcw, const float* __restrict__ fcb,
                     float* __restrict__ out) {
  int b = blockIdx.x;
  int lane = threadIdx.x;  // 64
  float p0 = 0.f, p1 = 0.f;
  #pragma unroll
  for (int k = lane; k < 2 * H_; k += 64) {
    float v = (k < H_) ? hf[b * H_ + k] : hb[b * H_ + (k - H_)];
    p0 += v * fcw[k];
    p1 += v * fcw[2 * H_ + k];
  }
  #pragma unroll
  for (int o = 32; o; o >>= 1) {
    p0 += __shfl_down(p0, o);
    p1 += __shfl_down(p1, o);
  }
  if (lane == 0) {
    out[b * 2 + 0] = p0 + fcb[0];
    out[b * 2 + 1] = p1 + fcb[1];
  }
}

extern "C" void kernel_launch(void* const* d_in, const int* in_sizes, int n_in,
                              void* d_out, int out_size, void* d_ws, size_t ws_size,
                              hipStream_t stream) {
  const int*   x    = (const int*)  d_in[0];
  const float* emb  = (const float*)d_in[1];
  const float* tsW  = (const float*)d_in[2];
  const float* wihf = (const float*)d_in[3];
  const float* whhf = (const float*)d_in[4];
  const float* bihf = (const float*)d_in[5];
  const float* bhhf = (const float*)d_in[6];
  const float* wihb = (const float*)d_in[7];
  // d_in[8] = w_hh_b: mathematically unused (only one backward step from zero state)
  const float* bihb = (const float*)d_in[9];
  const float* bhhb = (const float*)d_in[10];
  const float* fcw  = (const float*)d_in[11];
  const float* fcb  = (const float*)d_in[12];
  float* out = (float*)d_out;

  // workspace layout (244,058,112 bytes total)
  char* ws = (char*)d_ws;
  float* s     = (float*)(ws);                 //       2,048
  u16*   wfrag = (u16*)  (ws + 2048);          //     524,288
  u16*   feat  = (u16*)  (ws + 526336);        //  32,768,000
  u16*   xg    = (u16*)  (ws + 33294336);      // 209,715,200
  float* hf    = (float*)(ws + 243009536);     //     524,288
  float* hb    = (float*)(ws + 243533824);     //     524,288

  k_norm    <<<dim3(512),      dim3(256), 0, stream>>>(x, s);
  k_prep_whh<<<dim3(512),      dim3(512), 0, stream>>>(whhf, wfrag);
  k_feat    <<<dim3(64000),    dim3(256), 0, stream>>>(x, emb, tsW, s, feat);
  k_xg      <<<dim3(16, 800),  dim3(256), 0, stream>>>(feat, wihf, bihf, bhhf, xg);
  k_lstm_f  <<<dim3(32),       dim3(512), 0, stream>>>(wfrag, xg, hf);
  k_bwd     <<<dim3(512),      dim3(256), 0, stream>>>(feat, wihb, bihb, bhhb, hb);
  k_fc      <<<dim3(512),      dim3(64),  0, stream>>>(hf, hb, fcw, fcb, out);
}

// Round 2
// 976.490 us; speedup vs baseline: 1.0525x; 1.0525x over previous
//
#include <hip/hip_runtime.h>
#include <stdint.h>

// BiRNN on MI355X — round 2.
//  - backward LSTM = ONE step from zero state (only out[:, -1] consumed).
//  - forward scan: persistent 32 blocks x 512 thr, 16 batch rows/block.
//  - W_hh held ENTIRELY in registers as fp8 e4m3 (64 frags x 2 regs = 128/wave):
//    round-1 bf16 version spilled ~20 frags (VGPR cap 256 @ 2 waves/SIMD) ->
//    ~3500 cy/step scratch reloads. fp8 kills spills AND the 144KB/step LDS-W
//    traffic. Scaling: W*64, h*16 (dodges e4m3 subnormals), xg prescaled *1024
//    in k_xg, descale 2^-10 at epilogue. MFMA fp8 rate == bf16 rate.
//  - raw s_barrier with lgkmcnt(0)-only wait: xg prefetch (issued at step TOP)
//    stays in flight across the barrier (no vmcnt(0) drain like __syncthreads).
//  - h double-buffered in LDS (2 x 4224 B) -> one barrier per step.

typedef unsigned short u16;
typedef __bf16 bf16x8 __attribute__((ext_vector_type(8)));
typedef float  f32x4  __attribute__((ext_vector_type(4)));

#define B_    512
#define L_    200
#define EMB_  128
#define TDIM_ 10
#define IN_   138
#define INP_  160   // feat padded K (5 x 32)
#define H_    256
#define G4_   1024
#define T_    200
#define DS_   (1.0f/1024.0f)   // descale: (W*64)*(h*16), xg prescaled *1024

static __device__ __forceinline__ float bf2f(u16 u) {
  union { uint32_t i; float f; } v; v.i = ((uint32_t)u) << 16; return v.f;
}
static __device__ __forceinline__ u16 f2bf(float f) {
  __bf16 h = (__bf16)f; return __builtin_bit_cast(u16, h);
}
static __device__ __forceinline__ float bflo(uint32_t u) {
  return __builtin_bit_cast(float, (uint32_t)(u << 16));
}
static __device__ __forceinline__ float bfhi(uint32_t u) {
  return __builtin_bit_cast(float, (uint32_t)(u & 0xffff0000u));
}
static __device__ __forceinline__ float sigf(float x) {
  return __builtin_amdgcn_rcpf(1.0f + __expf(-x));
}
static __device__ __forceinline__ float tanh_(float x) {
  x = fminf(fmaxf(x, -15.f), 15.f);
  float e = __expf(2.0f * x);
  return (e - 1.0f) * __builtin_amdgcn_rcpf(e + 1.0f);
}
static __device__ __forceinline__ f32x4 mfma16(bf16x8 a, bf16x8 b, f32x4 c) {
  return __builtin_amdgcn_mfma_f32_16x16x32_bf16(a, b, c, 0, 0, 0);
}
static __device__ __forceinline__ f32x4 vzero4() {
  f32x4 v; v[0] = 0.f; v[1] = 0.f; v[2] = 0.f; v[3] = 0.f; return v;
}

// ---------------- K1: s[b] = sum_l t^2 ----------------
__global__ void k_norm(const int* __restrict__ x, float* __restrict__ s) {
  int b = blockIdx.x;
  int tid = threadIdx.x;
  float v = 0.f;
  if (tid < L_) {
    float t = (float)x[(b * L_ + tid) * 2];
    v = t * t;
  }
  #pragma unroll
  for (int o = 32; o; o >>= 1) v += __shfl_down(v, o);
  __shared__ float p[4];
  if ((tid & 63) == 0) p[tid >> 6] = v;
  __syncthreads();
  if (tid == 0) s[b] = p[0] + p[1] + p[2] + p[3];
}

// ---------------- K0b: W_hh fp32 -> frag-ordered fp8 e4m3, scaled *64 -------
// frag fid=(w*8+tt)*8+kp; dword idx = fid*128 + lane*2 + jq; A-frag lane
// (q=lane>>4, mm=lane&15) holds A[g=(w+8tt)*16+mm][k=kp*32+q*8+j], j=jq*4+0..3
__global__ void k_prep_w8(const float* __restrict__ whh, int* __restrict__ wf8) {
  int idx = blockIdx.x * blockDim.x + threadIdx.x;  // < 65536 dwords
  int jq = idx & 1;
  int lane = (idx >> 1) & 63;
  int fid = idx >> 7;
  int kp = fid & 7, tt = (fid >> 3) & 7, w = fid >> 6;
  int mm = lane & 15, q = lane >> 4;
  int g = (w + 8 * tt) * 16 + mm;
  int k = kp * 32 + q * 8 + jq * 4;
  const float* src = whh + g * 256 + k;
  int d = __builtin_amdgcn_cvt_pk_fp8_f32(src[0] * 64.f, src[1] * 64.f, 0, false);
  d     = __builtin_amdgcn_cvt_pk_fp8_f32(src[2] * 64.f, src[3] * 64.f, d, true);
  wf8[idx] = d;
}

// ---------------- K2: features (t_emb normalized | l_emb | pad) bf16 --------
__global__ void k_feat(const int* __restrict__ x, const float* __restrict__ emb,
                       const float* __restrict__ tsW, const float* __restrict__ s,
                       u16* __restrict__ feat) {
  int idx = blockIdx.x * blockDim.x + threadIdx.x;
  if (idx >= B_ * L_ * INP_) return;
  int c = idx % INP_;
  int row = idx / INP_;
  int b = row / L_;
  float v = 0.f;
  if (c < TDIM_) {
    float t = (float)x[row * 2 + 0];
    float wd = tsW[c];
    float den = fmaxf(fabsf(wd) * sqrtf(s[b]), 1e-12f);
    v = t * wd / den;
  } else if (c < IN_) {
    int id = x[row * 2 + 1];
    int idc = id < 0 ? 0 : id;
    float e = emb[(long)idc * EMB_ + (c - TDIM_)];
    v = (id >= 0) ? e : 0.f;
  }
  feat[idx] = f2bf(v);
}

// ---------------- K3: xg = (feat @ W_ih^T + b_ih + b_hh) * 1024, bf16 -------
// M-tile 128 x N-tile 128, grid (8, 800). Epilogue transposes through LDS for
// coalesced 16B stores (round-1 did scattered 2B stores).
__global__ __launch_bounds__(256) void k_xg(
    const u16* __restrict__ feat, const float* __restrict__ wih,
    const float* __restrict__ bih, const float* __restrict__ bhh,
    u16* __restrict__ xg) {
  __shared__ u16 Bs[128 * 168];  // 43008 B; reused as 128x136 out-tile (34816 B)
  const int nt = blockIdx.x;   // 0..7
  const int mt = blockIdx.y;   // 0..799
  const int tid = threadIdx.x;
  const int w = tid >> 6, lane = tid & 63;
  const int q = lane >> 4, nm = lane & 15;
  for (int i = tid; i < 128 * 168; i += 256) {
    int gl = i / 168, f = i % 168;
    float v = (f < IN_) ? wih[(nt * 128 + gl) * IN_ + f] : 0.f;
    Bs[i] = f2bf(v);
  }
  float bias[8];
  #pragma unroll
  for (int nu = 0; nu < 8; ++nu) {
    int g = nt * 128 + nu * 16 + nm;
    bias[nu] = bih[g] + bhh[g];
  }
  __syncthreads();
  f32x4 acc[2][8];
  #pragma unroll
  for (int m = 0; m < 2; ++m)
    #pragma unroll
    for (int nu = 0; nu < 8; ++nu) acc[m][nu] = vzero4();
  const u16* arow = feat + (long)(mt * 128 + w * 32) * INP_;
  #pragma unroll
  for (int kp = 0; kp < 5; ++kp) {
    bf16x8 a0 = *(const bf16x8*)(arow + (nm * INP_ + kp * 32 + q * 8));
    bf16x8 a1 = *(const bf16x8*)(arow + ((16 + nm) * INP_ + kp * 32 + q * 8));
    #pragma unroll
    for (int nu = 0; nu < 8; ++nu) {
      bf16x8 bb = *(const bf16x8*)&Bs[(nu * 16 + nm) * 168 + kp * 32 + q * 8];
      acc[0][nu] = mfma16(a0, bb, acc[0][nu]);
      acc[1][nu] = mfma16(a1, bb, acc[1][nu]);
    }
  }
  __syncthreads();  // done reading Bs; reuse as out-tile
  u16* Os = Bs;     // [128 rows][136 cols] u16, stride 136 (272 B, 16B-aligned)
  #pragma unroll
  for (int nu = 0; nu < 8; ++nu) {
    #pragma unroll
    for (int m = 0; m < 2; ++m) {
      #pragma unroll
      for (int r = 0; r < 4; ++r) {
        int row = w * 32 + m * 16 + 4 * q + r;
        Os[row * 136 + nu * 16 + nm] = f2bf((acc[m][nu][r] + bias[nu]) * 1024.f);
      }
    }
  }
  __syncthreads();
  // coalesced copy-out: 128 rows x 256 B
  #pragma unroll
  for (int it = 0; it < 8; ++it) {
    int flat = it * 256 + tid;
    int row = flat >> 4, c = flat & 15;
    uint4 v = *(const uint4*)&Os[row * 136 + c * 8];
    *(uint4*)&xg[(long)(mt * 128 + row) * G4_ + nt * 128 + c * 8] = v;
  }
}

// ---------------- K4: forward LSTM scan, fp8-weight-resident ----------------
// 32 blocks x 512 thr. Wave w owns m-tiles {w+8*tt}: tt {0,1}=i {2,3}=f
// {4,5}=g {6,7}=o; lane-local c/h update. All 64 W-frags in regs (128/wave).
__global__ __launch_bounds__(512, 2) void k_lstm_f(
    const long* __restrict__ wf8, const u16* __restrict__ xg,
    float* __restrict__ hf) {
  __shared__ int hls[2][16 * 66];  // fp8 h, row stride 264 B, double buffer
  const int tid = threadIdx.x;
  const int w = tid >> 6;
  const int lane = tid & 63;
  const int q = lane >> 4;
  const int nn = lane & 15;
  const int b = blockIdx.x * 16 + nn;

  long wv[64];  // fp8 A-frags: wv[tt*8+kp], 2 regs each -> 128 regs/wave
  #pragma unroll
  for (int fi = 0; fi < 64; ++fi)
    wv[fi] = wf8[(long)(w * 64 + fi) * 64 + lane];

  for (int i = tid; i < 16 * 66; i += 512) hls[0][i] = 0;

  const u16* xgb = xg + (long)b * (L_ * G4_);
  uint2 pf[8];
  #pragma unroll
  for (int tt = 0; tt < 8; ++tt)
    pf[tt] = *(const uint2*)(xgb + (w + 8 * tt) * 16 + 4 * q);
  f32x4 cst[2];
  cst[0] = vzero4();
  cst[1] = vzero4();
  __syncthreads();

  #pragma unroll 1
  for (int t = 0; t < T_; ++t) {
    // acc init = xg*1024 (prescaled in k_xg)
    f32x4 acc[8];
    #pragma unroll
    for (int tt = 0; tt < 8; ++tt) {
      acc[tt][0] = bflo(pf[tt].x);
      acc[tt][1] = bfhi(pf[tt].x);
      acc[tt][2] = bflo(pf[tt].y);
      acc[tt][3] = bfhi(pf[tt].y);
    }
    // issue next step's prefetch NOW: ~full step of latency hiding, and the
    // barrier below waits lgkmcnt only, so these stay in flight across it.
    const u16* xn = xgb + (long)(t + 1 < T_ ? t + 1 : t) * G4_;
    #pragma unroll
    for (int tt = 0; tt < 8; ++tt)
      pf[tt] = *(const uint2*)(xn + (w + 8 * tt) * 16 + 4 * q);
    // g_pre += (64*W_hh).(16*h)
    const int* hr = hls[t & 1];
    #pragma unroll
    for (int kp = 0; kp < 8; ++kp) {
      long bh = *(const long*)&hr[nn * 66 + kp * 8 + q * 2];
      #pragma unroll
      for (int tt = 0; tt < 8; ++tt)
        acc[tt] = __builtin_amdgcn_mfma_f32_16x16x32_fp8_fp8(
            wv[tt * 8 + kp], bh, acc[tt], 0, 0, 0);
    }
    int* hw = hls[1 - (t & 1)];
    #pragma unroll
    for (int j = 0; j < 2; ++j) {
      f32x4 hv;
      #pragma unroll
      for (int r = 0; r < 4; ++r) {
        float iv = acc[0 + j][r] * DS_;
        float fv = acc[2 + j][r] * DS_;
        float gv = acc[4 + j][r] * DS_;
        float ov = acc[6 + j][r] * DS_;
        float c = sigf(fv) * cst[j][r] + sigf(iv) * tanh_(gv);
        float h = sigf(ov) * tanh_(c);
        cst[j][r] = c;
        hv[r] = h;
      }
      int pk = __builtin_amdgcn_cvt_pk_fp8_f32(hv[0] * 16.f, hv[1] * 16.f, 0, false);
      pk     = __builtin_amdgcn_cvt_pk_fp8_f32(hv[2] * 16.f, hv[3] * 16.f, pk, true);
      hw[nn * 66 + 4 * w + 32 * j + q] = pk;
      if (t == T_ - 1)
        *(f32x4*)&hf[(long)b * H_ + 16 * w + 128 * j + 4 * q] = hv;
    }
    // raw barrier: wait DS only (lgkmcnt(0)); vmcnt prefetch NOT drained.
    __asm__ volatile("" ::: "memory");
    __builtin_amdgcn_s_waitcnt(0xc07f);
    __builtin_amdgcn_s_barrier();
    __asm__ volatile("" ::: "memory");
  }
}

// ---------------- K5: backward LSTM = ONE step from zero state at l=L-1 -----
// 8 batch rows/block amortize the 565 KB weight read; forget gate skipped
// (c0 = 0 -> sig(f)*c0 = 0).
__global__ __launch_bounds__(256) void k_bwd(
    const u16* __restrict__ feat, const float* __restrict__ wih,
    const float* __restrict__ bih, const float* __restrict__ bhh,
    float* __restrict__ hb) {
  const int b0 = blockIdx.x * 8;
  const int tid = threadIdx.x;
  __shared__ float fv[8][IN_];
  for (int i = tid; i < 8 * IN_; i += 256) {
    int r = i / IN_, c = i % IN_;
    fv[r][c] = bf2f(feat[((long)(b0 + r) * L_ + (L_ - 1)) * INP_ + c]);
  }
  __syncthreads();
  float gi[8], gg[8], go[8];
  float bi_ = bih[tid] + bhh[tid];
  float bg_ = bih[2 * H_ + tid] + bhh[2 * H_ + tid];
  float bo_ = bih[3 * H_ + tid] + bhh[3 * H_ + tid];
  #pragma unroll
  for (int r = 0; r < 8; ++r) { gi[r] = bi_; gg[r] = bg_; go[r] = bo_; }
  const float* wi_ = wih + (long)tid * IN_;
  const float* wg_ = wih + (long)(2 * H_ + tid) * IN_;
  const float* wo_ = wih + (long)(3 * H_ + tid) * IN_;
  for (int f = 0; f < IN_; ++f) {
    float a = wi_[f], gc = wg_[f], oc = wo_[f];
    #pragma unroll
    for (int r = 0; r < 8; ++r) {
      float x = fv[r][f];
      gi[r] += a * x;
      gg[r] += gc * x;
      go[r] += oc * x;
    }
  }
  #pragma unroll
  for (int r = 0; r < 8; ++r) {
    float c = sigf(gi[r]) * tanh_(gg[r]);
    hb[(long)(b0 + r) * H_ + tid] = sigf(go[r]) * tanh_(c);
  }
}

// ---------------- K6: fc head ----------------
__global__ void k_fc(const float* __restrict__ hf, const float* __restrict__ hb,
                     const float* __restrict__ fcw, const float* __restrict__ fcb,
                     float* __restrict__ out) {
  int b = blockIdx.x;
  int lane = threadIdx.x;  // 64
  float p0 = 0.f, p1 = 0.f;
  #pragma unroll
  for (int k = lane; k < 2 * H_; k += 64) {
    float v = (k < H_) ? hf[b * H_ + k] : hb[b * H_ + (k - H_)];
    p0 += v * fcw[k];
    p1 += v * fcw[2 * H_ + k];
  }
  #pragma unroll
  for (int o = 32; o; o >>= 1) {
    p0 += __shfl_down(p0, o);
    p1 += __shfl_down(p1, o);
  }
  if (lane == 0) {
    out[b * 2 + 0] = p0 + fcb[0];
    out[b * 2 + 1] = p1 + fcb[1];
  }
}

extern "C" void kernel_launch(void* const* d_in, const int* in_sizes, int n_in,
                              void* d_out, int out_size, void* d_ws, size_t ws_size,
                              hipStream_t stream) {
  const int*   x    = (const int*)  d_in[0];
  const float* emb  = (const float*)d_in[1];
  const float* tsW  = (const float*)d_in[2];
  const float* wihf = (const float*)d_in[3];
  const float* whhf = (const float*)d_in[4];
  const float* bihf = (const float*)d_in[5];
  const float* bhhf = (const float*)d_in[6];
  const float* wihb = (const float*)d_in[7];
  // d_in[8] = w_hh_b: unused (one backward step from zero state)
  const float* bihb = (const float*)d_in[9];
  const float* bhhb = (const float*)d_in[10];
  const float* fcw  = (const float*)d_in[11];
  const float* fcb  = (const float*)d_in[12];
  float* out = (float*)d_out;

  // workspace layout (243,795,968 bytes total)
  char* ws = (char*)d_ws;
  float* s    = (float*)(ws);                  //       2,048
  int*   wf8  = (int*)  (ws + 2048);           //     262,144 (fp8 W_hh frags)
  u16*   feat = (u16*)  (ws + 264192);         //  32,768,000
  u16*   xg   = (u16*)  (ws + 33032192);       // 209,715,200
  float* hf   = (float*)(ws + 242747392);      //     524,288
  float* hb   = (float*)(ws + 243271680);      //     524,288

  k_norm   <<<dim3(512),     dim3(256), 0, stream>>>(x, s);
  k_prep_w8<<<dim3(256),     dim3(256), 0, stream>>>(whhf, wf8);
  k_feat   <<<dim3(64000),   dim3(256), 0, stream>>>(x, emb, tsW, s, feat);
  k_xg     <<<dim3(8, 800),  dim3(256), 0, stream>>>(feat, wihf, bihf, bhhf, xg);
  k_lstm_f <<<dim3(32),      dim3(512), 0, stream>>>((const long*)wf8, xg, hf);
  k_bwd    <<<dim3(64),      dim3(256), 0, stream>>>(feat, wihb, bihb, bhhb, hb);
  k_fc     <<<dim3(512),     dim3(64),  0, stream>>>(hf, hb, fcw, fcb, out);
}

// Round 4
// 884.567 us; speedup vs baseline: 1.1619x; 1.1039x over previous
//
#include <hip/hip_runtime.h>
#include <stdint.h>

// BiRNN on MI355X — round 4 (round 3 + compile fix: __exp2f -> __builtin_amdgcn_exp2f).
//  - backward LSTM = ONE step from zero state (only out[:, -1] consumed).
//  - forward scan: persistent 32 blocks x 512 thr, 16 batch rows/block.
//  - ROUND-2 BUG: `long wv[64]` never got SROA'd -> lived in scratch, 256KB/
//    block/step of L2 reloads (~4000 cy/step; VGPR_Count=100 was the tell).
//    FIX: 48 frags as NAMED long scalars (kp 0..5) + asm "+v" pin in the loop,
//    16 frags (kp 6,7) LDS-resident (64 KB; reads hide under MFMA issue).
//  - matrix floor at 32 blocks: 2 waves/SIMD x 64 mfma x ~19.4cy = ~2484
//    cy/step; epilogue VALU co-issues (m114). Target ~240us for the scan.
//  - raw s_barrier with lgkmcnt-only wait keeps xg prefetch in flight.

typedef unsigned short u16;
typedef __bf16 bf16x8 __attribute__((ext_vector_type(8)));
typedef float  f32x4  __attribute__((ext_vector_type(4)));

#define B_    512
#define L_    200
#define EMB_  128
#define TDIM_ 10
#define IN_   138
#define INP_  160   // feat padded K (5 x 32)
#define H_    256
#define G4_   1024
#define T_    200
#define DS_   (1.0f/1024.0f)   // descale: (W*64)*(h*16), xg prescaled *1024
#define LOG2E 1.4426950408889634f
#define EXP2(x) __builtin_amdgcn_exp2f(x)

static __device__ __forceinline__ float bf2f(u16 u) {
  union { uint32_t i; float f; } v; v.i = ((uint32_t)u) << 16; return v.f;
}
static __device__ __forceinline__ u16 f2bf(float f) {
  __bf16 h = (__bf16)f; return __builtin_bit_cast(u16, h);
}
static __device__ __forceinline__ float bflo(uint32_t u) {
  return __builtin_bit_cast(float, (uint32_t)(u << 16));
}
static __device__ __forceinline__ float bfhi(uint32_t u) {
  return __builtin_bit_cast(float, (uint32_t)(u & 0xffff0000u));
}
static __device__ __forceinline__ float sigf(float x) {
  return __builtin_amdgcn_rcpf(1.0f + EXP2(-x * LOG2E));
}
static __device__ __forceinline__ float tanh_(float x) {
  x = fminf(fmaxf(x, -15.f), 15.f);
  float e = EXP2(2.0f * LOG2E * x);
  return (e - 1.0f) * __builtin_amdgcn_rcpf(e + 1.0f);
}
static __device__ __forceinline__ f32x4 mfma16(bf16x8 a, bf16x8 b, f32x4 c) {
  return __builtin_amdgcn_mfma_f32_16x16x32_bf16(a, b, c, 0, 0, 0);
}
static __device__ __forceinline__ f32x4 vzero4() {
  f32x4 v; v[0] = 0.f; v[1] = 0.f; v[2] = 0.f; v[3] = 0.f; return v;
}

// ---------------- K1: s[b] = sum_l t^2 ----------------
__global__ void k_norm(const int* __restrict__ x, float* __restrict__ s) {
  int b = blockIdx.x;
  int tid = threadIdx.x;
  float v = 0.f;
  if (tid < L_) {
    float t = (float)x[(b * L_ + tid) * 2];
    v = t * t;
  }
  #pragma unroll
  for (int o = 32; o; o >>= 1) v += __shfl_down(v, o);
  __shared__ float p[4];
  if ((tid & 63) == 0) p[tid >> 6] = v;
  __syncthreads();
  if (tid == 0) s[b] = p[0] + p[1] + p[2] + p[3];
}

// ---------------- K0b: W_hh fp32 -> frag-ordered fp8 e4m3, scaled *64 -------
// frag fid=(w*8+tt)*8+kp; dword idx = fid*128 + lane*2 + jq; A-frag lane
// (q=lane>>4, mm=lane&15) holds A[g=(w+8tt)*16+mm][k=kp*32+q*8+j], j=jq*4+0..3
__global__ void k_prep_w8(const float* __restrict__ whh, int* __restrict__ wf8) {
  int idx = blockIdx.x * blockDim.x + threadIdx.x;  // < 65536 dwords
  int jq = idx & 1;
  int lane = (idx >> 1) & 63;
  int fid = idx >> 7;
  int kp = fid & 7, tt = (fid >> 3) & 7, w = fid >> 6;
  int mm = lane & 15, q = lane >> 4;
  int g = (w + 8 * tt) * 16 + mm;
  int k = kp * 32 + q * 8 + jq * 4;
  const float* src = whh + g * 256 + k;
  int d = __builtin_amdgcn_cvt_pk_fp8_f32(src[0] * 64.f, src[1] * 64.f, 0, false);
  d     = __builtin_amdgcn_cvt_pk_fp8_f32(src[2] * 64.f, src[3] * 64.f, d, true);
  wf8[idx] = d;
}

// ---------------- K2: features (t_emb normalized | l_emb | pad) bf16 --------
__global__ void k_feat(const int* __restrict__ x, const float* __restrict__ emb,
                       const float* __restrict__ tsW, const float* __restrict__ s,
                       u16* __restrict__ feat) {
  int idx = blockIdx.x * blockDim.x + threadIdx.x;
  if (idx >= B_ * L_ * INP_) return;
  int c = idx % INP_;
  int row = idx / INP_;
  int b = row / L_;
  float v = 0.f;
  if (c < TDIM_) {
    float t = (float)x[row * 2 + 0];
    float wd = tsW[c];
    float den = fmaxf(fabsf(wd) * sqrtf(s[b]), 1e-12f);
    v = t * wd / den;
  } else if (c < IN_) {
    int id = x[row * 2 + 1];
    int idc = id < 0 ? 0 : id;
    float e = emb[(long)idc * EMB_ + (c - TDIM_)];
    v = (id >= 0) ? e : 0.f;
  }
  feat[idx] = f2bf(v);
}

// ---------------- K3: xg = (feat @ W_ih^T + b_ih + b_hh) * 1024, bf16 -------
// M-tile 128 x N-tile 256, grid (4, 800), 512 thr. Halves feat re-reads vs
// round 2 (131 MB). Epilogue transposes through LDS for coalesced 16B stores.
__global__ __launch_bounds__(512) void k_xg(
    const u16* __restrict__ feat, const float* __restrict__ wih,
    const float* __restrict__ bih, const float* __restrict__ bhh,
    u16* __restrict__ xg) {
  __shared__ u16 Bs[256 * 176];  // 90112 B; reused as 128x264 out-tile
  const int nt = blockIdx.x;   // 0..3
  const int mt = blockIdx.y;   // 0..799
  const int tid = threadIdx.x;
  const int w = tid >> 6, lane = tid & 63;
  const int q = lane >> 4, nm = lane & 15;
  // stage W rows [nt*256, nt*256+256) as bf16, padded to 176 cols; float2 loads
  for (int i2 = tid; i2 < 256 * 88; i2 += 512) {
    int gl = i2 / 88, f2 = (i2 % 88) * 2;
    int pk = 0;
    if (f2 < IN_) {
      float2 v = *(const float2*)(wih + (long)(nt * 256 + gl) * IN_ + f2);
      pk = (int)f2bf(v.x) | ((int)f2bf(v.y) << 16);
    }
    *(int*)&Bs[gl * 176 + f2] = pk;
  }
  float bias[16];
  #pragma unroll
  for (int nu = 0; nu < 16; ++nu) {
    int g = nt * 256 + nu * 16 + nm;
    bias[nu] = bih[g] + bhh[g];
  }
  __syncthreads();
  f32x4 acc[16];
  #pragma unroll
  for (int nu = 0; nu < 16; ++nu) acc[nu] = vzero4();
  const u16* arow = feat + (long)(mt * 128 + w * 16) * INP_;
  #pragma unroll
  for (int kp = 0; kp < 5; ++kp) {
    bf16x8 a = *(const bf16x8*)(arow + (nm * INP_ + kp * 32 + q * 8));
    #pragma unroll
    for (int nu = 0; nu < 16; ++nu) {
      bf16x8 bb = *(const bf16x8*)&Bs[(nu * 16 + nm) * 176 + kp * 32 + q * 8];
      acc[nu] = mfma16(a, bb, acc[nu]);
    }
  }
  __syncthreads();  // done reading Bs; reuse as out-tile
  u16* Os = Bs;     // [128 rows][264 cols] u16 (528 B rows, 16B-aligned)
  #pragma unroll
  for (int nu = 0; nu < 16; ++nu) {
    #pragma unroll
    for (int r = 0; r < 4; ++r) {
      int row = w * 16 + 4 * q + r;
      Os[row * 264 + nu * 16 + nm] = f2bf((acc[nu][r] + bias[nu]) * 1024.f);
    }
  }
  __syncthreads();
  // coalesced copy-out: 128 rows x 512 B
  #pragma unroll
  for (int it = 0; it < 8; ++it) {
    int flat = it * 512 + tid;
    int row = flat >> 5, c = flat & 31;
    uint4 v = *(const uint4*)&Os[row * 264 + c * 8];
    *(uint4*)&xg[(long)(mt * 128 + row) * G4_ + nt * 256 + c * 8] = v;
  }
}

// ---------------- K4: forward LSTM scan, fp8-weight-resident ----------------
// 32 blocks x 512 thr. Wave w owns m-tiles {w+8*tt}: tt {0,1}=i {2,3}=f
// {4,5}=g {6,7}=o; lane-local c/h update. Weights: kp 0..5 in NAMED regs
// (96 VGPRs, asm-pinned), kp 6,7 in LDS.
#define F8(A, B, C) __builtin_amdgcn_mfma_f32_16x16x32_fp8_fp8((A), (B), (C), 0, 0, 0)
#define WLD(tt) \
  long w##tt##_0 = wp[((tt) * 8 + 0) * 64]; \
  long w##tt##_1 = wp[((tt) * 8 + 1) * 64]; \
  long w##tt##_2 = wp[((tt) * 8 + 2) * 64]; \
  long w##tt##_3 = wp[((tt) * 8 + 3) * 64]; \
  long w##tt##_4 = wp[((tt) * 8 + 4) * 64]; \
  long w##tt##_5 = wp[((tt) * 8 + 5) * 64];
#define MK(kp) { \
  long bh = *(const long*)&hr[hbase + (kp) * 8]; \
  acc0 = F8(w0_##kp, bh, acc0); acc1 = F8(w1_##kp, bh, acc1); \
  acc2 = F8(w2_##kp, bh, acc2); acc3 = F8(w3_##kp, bh, acc3); \
  acc4 = F8(w4_##kp, bh, acc4); acc5 = F8(w5_##kp, bh, acc5); \
  acc6 = F8(w6_##kp, bh, acc6); acc7 = F8(w7_##kp, bh, acc7); }
#define MKL(slot, kp) { \
  long bh = *(const long*)&hr[hbase + (kp) * 8]; \
  const long* lw = ldsW + (w * 16 + (slot) * 8) * 64 + lane; \
  acc0 = F8(lw[0 * 64], bh, acc0); acc1 = F8(lw[1 * 64], bh, acc1); \
  acc2 = F8(lw[2 * 64], bh, acc2); acc3 = F8(lw[3 * 64], bh, acc3); \
  acc4 = F8(lw[4 * 64], bh, acc4); acc5 = F8(lw[5 * 64], bh, acc5); \
  acc6 = F8(lw[6 * 64], bh, acc6); acc7 = F8(lw[7 * 64], bh, acc7); }
#define AINIT(i) \
  f32x4 acc##i; acc##i[0] = bflo(pf##i.x); acc##i[1] = bfhi(pf##i.x); \
  acc##i[2] = bflo(pf##i.y); acc##i[3] = bfhi(pf##i.y);
#define PFL(i) pf##i = *(const uint2*)(xn + ((w + 8 * (i)) * 16 + 4 * q));
#define EPI(jj, aI, aF, aG, aO, cs) { \
  f32x4 hv; \
  _Pragma("unroll") \
  for (int r = 0; r < 4; ++r) { \
    float si = __builtin_amdgcn_rcpf(1.f + EXP2(aI[r] * c_sig)); \
    float sf = __builtin_amdgcn_rcpf(1.f + EXP2(aF[r] * c_sig)); \
    float so = __builtin_amdgcn_rcpf(1.f + EXP2(aO[r] * c_sig)); \
    float tg = 1.f - 2.f * __builtin_amdgcn_rcpf(1.f + EXP2(aG[r] * c_tg)); \
    float c = sf * cs[r] + si * tg; \
    float tc = 1.f - 2.f * __builtin_amdgcn_rcpf(1.f + EXP2(c * c_tc)); \
    cs[r] = c; hv[r] = so * tc; \
  } \
  int pk = __builtin_amdgcn_cvt_pk_fp8_f32(hv[0] * 16.f, hv[1] * 16.f, 0, false); \
  pk     = __builtin_amdgcn_cvt_pk_fp8_f32(hv[2] * 16.f, hv[3] * 16.f, pk, true); \
  hw[nn * 66 + 4 * w + 32 * (jj) + q] = pk; \
  if (t == T_ - 1) *(f32x4*)&hf[(long)b * H_ + 16 * w + 128 * (jj) + 4 * q] = hv; }

__global__ __launch_bounds__(512, 2) void k_lstm_f(
    const long* __restrict__ wf8, const u16* __restrict__ xg,
    float* __restrict__ hf) {
  __shared__ long ldsW[128 * 64];   // 65536 B: kp=6,7 frags (8 waves x 16)
  __shared__ int hls[2][16 * 66];   // 8448 B: fp8 h, double buffer
  const int tid = threadIdx.x;
  const int w = tid >> 6;
  const int lane = tid & 63;
  const int q = lane >> 4;
  const int nn = lane & 15;
  const int b = blockIdx.x * 16 + nn;
  const int hbase = nn * 66 + (q << 1);
  const float c_sig = -DS_ * LOG2E;
  const float c_tg  = 2.f * DS_ * LOG2E;
  const float c_tc  = 2.f * LOG2E;

  const long* wp = wf8 + (long)(w * 64) * 64 + lane;
  WLD(0) WLD(1) WLD(2) WLD(3) WLD(4) WLD(5) WLD(6) WLD(7)
  #pragma unroll
  for (int tt = 0; tt < 8; ++tt) {
    ldsW[(w * 16 + tt) * 64 + lane]     = wp[(tt * 8 + 6) * 64];
    ldsW[(w * 16 + 8 + tt) * 64 + lane] = wp[(tt * 8 + 7) * 64];
  }
  for (int i = tid; i < 16 * 66; i += 512) hls[0][i] = 0;

  const u16* xgb = xg + (long)b * (L_ * G4_);
  uint2 pf0, pf1, pf2, pf3, pf4, pf5, pf6, pf7;
  {
    const u16* xn = xgb;
    PFL(0) PFL(1) PFL(2) PFL(3) PFL(4) PFL(5) PFL(6) PFL(7)
  }
  f32x4 cst0 = vzero4(), cst1 = vzero4();
  __syncthreads();

  #pragma unroll 1
  for (int t = 0; t < T_; ++t) {
    // pin the 48 weight frags in VGPRs every iteration (defeats remat/spill)
    asm volatile("" :
      "+v"(w0_0), "+v"(w0_1), "+v"(w0_2), "+v"(w0_3), "+v"(w0_4), "+v"(w0_5),
      "+v"(w1_0), "+v"(w1_1), "+v"(w1_2), "+v"(w1_3), "+v"(w1_4), "+v"(w1_5),
      "+v"(w2_0), "+v"(w2_1), "+v"(w2_2), "+v"(w2_3), "+v"(w2_4), "+v"(w2_5),
      "+v"(w3_0), "+v"(w3_1), "+v"(w3_2), "+v"(w3_3), "+v"(w3_4), "+v"(w3_5),
      "+v"(w4_0), "+v"(w4_1), "+v"(w4_2), "+v"(w4_3), "+v"(w4_4), "+v"(w4_5),
      "+v"(w5_0), "+v"(w5_1), "+v"(w5_2), "+v"(w5_3), "+v"(w5_4), "+v"(w5_5),
      "+v"(w6_0), "+v"(w6_1), "+v"(w6_2), "+v"(w6_3), "+v"(w6_4), "+v"(w6_5),
      "+v"(w7_0), "+v"(w7_1), "+v"(w7_2), "+v"(w7_3), "+v"(w7_4), "+v"(w7_5));
    AINIT(0) AINIT(1) AINIT(2) AINIT(3) AINIT(4) AINIT(5) AINIT(6) AINIT(7)
    // issue next step's xg prefetch NOW; barrier below is lgkm-only so these
    // stay in flight across it.
    {
      const u16* xn = xgb + (long)(t + 1 < T_ ? t + 1 : t) * G4_;
      PFL(0) PFL(1) PFL(2) PFL(3) PFL(4) PFL(5) PFL(6) PFL(7)
    }
    const int* hr = hls[t & 1];
    MKL(0, 6) MKL(1, 7)   // LDS weights first: ds_reads issue early
    MK(0) MK(1) MK(2) MK(3) MK(4) MK(5)
    int* hw = hls[1 - (t & 1)];
    EPI(0, acc0, acc2, acc4, acc6, cst0)
    EPI(1, acc1, acc3, acc5, acc7, cst1)
    // raw barrier: wait DS only (lgkmcnt(0)); vmcnt prefetch NOT drained.
    __asm__ volatile("" ::: "memory");
    __builtin_amdgcn_s_waitcnt(0xc07f);
    __builtin_amdgcn_s_barrier();
    __asm__ volatile("" ::: "memory");
  }
}

// ---------------- K5: backward LSTM = ONE step from zero state at l=L-1 -----
__global__ __launch_bounds__(256) void k_bwd(
    const u16* __restrict__ feat, const float* __restrict__ wih,
    const float* __restrict__ bih, const float* __restrict__ bhh,
    float* __restrict__ hb) {
  const int b0 = blockIdx.x * 8;
  const int tid = threadIdx.x;
  __shared__ float fv[8][IN_];
  for (int i = tid; i < 8 * IN_; i += 256) {
    int r = i / IN_, c = i % IN_;
    fv[r][c] = bf2f(feat[((long)(b0 + r) * L_ + (L_ - 1)) * INP_ + c]);
  }
  __syncthreads();
  float gi[8], gg[8], go[8];
  float bi_ = bih[tid] + bhh[tid];
  float bg_ = bih[2 * H_ + tid] + bhh[2 * H_ + tid];
  float bo_ = bih[3 * H_ + tid] + bhh[3 * H_ + tid];
  #pragma unroll
  for (int r = 0; r < 8; ++r) { gi[r] = bi_; gg[r] = bg_; go[r] = bo_; }
  const float* wi_ = wih + (long)tid * IN_;
  const float* wg_ = wih + (long)(2 * H_ + tid) * IN_;
  const float* wo_ = wih + (long)(3 * H_ + tid) * IN_;
  for (int f = 0; f < IN_; ++f) {
    float a = wi_[f], gc = wg_[f], oc = wo_[f];
    #pragma unroll
    for (int r = 0; r < 8; ++r) {
      float x = fv[r][f];
      gi[r] += a * x;
      gg[r] += gc * x;
      go[r] += oc * x;
    }
  }
  #pragma unroll
  for (int r = 0; r < 8; ++r) {
    float c = sigf(gi[r]) * tanh_(gg[r]);
    hb[(long)(b0 + r) * H_ + tid] = sigf(go[r]) * tanh_(c);
  }
}

// ---------------- K6: fc head ----------------
__global__ void k_fc(const float* __restrict__ hf, const float* __restrict__ hb,
                     const float* __restrict__ fcw, const float* __restrict__ fcb,
                     float* __restrict__ out) {
  int b = blockIdx.x;
  int lane = threadIdx.x;  // 64
  float p0 = 0.f, p1 = 0.f;
  #pragma unroll
  for (int k = lane; k < 2 * H_; k += 64) {
    float v = (k < H_) ? hf[b * H_ + k] : hb[b * H_ + (k - H_)];
    p0 += v * fcw[k];
    p1 += v * fcw[2 * H_ + k];
  }
  #pragma unroll
  for (int o = 32; o; o >>= 1) {
    p0 += __shfl_down(p0, o);
    p1 += __shfl_down(p1, o);
  }
  if (lane == 0) {
    out[b * 2 + 0] = p0 + fcb[0];
    out[b * 2 + 1] = p1 + fcb[1];
  }
}

extern "C" void kernel_launch(void* const* d_in, const int* in_sizes, int n_in,
                              void* d_out, int out_size, void* d_ws, size_t ws_size,
                              hipStream_t stream) {
  const int*   x    = (const int*)  d_in[0];
  const float* emb  = (const float*)d_in[1];
  const float* tsW  = (const float*)d_in[2];
  const float* wihf = (const float*)d_in[3];
  const float* whhf = (const float*)d_in[4];
  const float* bihf = (const float*)d_in[5];
  const float* bhhf = (const float*)d_in[6];
  const float* wihb = (const float*)d_in[7];
  // d_in[8] = w_hh_b: unused (one backward step from zero state)
  const float* bihb = (const float*)d_in[9];
  const float* bhhb = (const float*)d_in[10];
  const float* fcw  = (const float*)d_in[11];
  const float* fcb  = (const float*)d_in[12];
  float* out = (float*)d_out;

  // workspace layout (243,795,968 bytes total — proven to fit in round 1/2)
  char* ws = (char*)d_ws;
  float* s    = (float*)(ws);                  //       2,048
  int*   wf8  = (int*)  (ws + 2048);           //     262,144 (fp8 W_hh frags)
  u16*   feat = (u16*)  (ws + 264192);         //  32,768,000
  u16*   xg   = (u16*)  (ws + 33032192);       // 209,715,200
  float* hf   = (float*)(ws + 242747392);      //     524,288
  float* hb   = (float*)(ws + 243271680);      //     524,288

  k_norm   <<<dim3(512),     dim3(256), 0, stream>>>(x, s);
  k_prep_w8<<<dim3(256),     dim3(256), 0, stream>>>(whhf, wf8);
  k_feat   <<<dim3(64000),   dim3(256), 0, stream>>>(x, emb, tsW, s, feat);
  k_xg     <<<dim3(4, 800),  dim3(512), 0, stream>>>(feat, wihf, bihf, bhhf, xg);
  k_lstm_f <<<dim3(32),      dim3(512), 0, stream>>>((const long*)wf8, xg, hf);
  k_bwd    <<<dim3(64),      dim3(256), 0, stream>>>(feat, wihb, bihb, bhhb, hb);
  k_fc     <<<dim3(512),     dim3(64),  0, stream>>>(hf, hb, fcw, fcb, out);
}

// Round 5
// 804.269 us; speedup vs baseline: 1.2779x; 1.0998x over previous
//
#include <hip/hip_runtime.h>
#include <stdint.h>

// BiRNN on MI355X — round 5.
//  - backward LSTM = ONE step from zero state (only out[:, -1] consumed).
//  - forward scan: persistent 32 blocks x 512 thr, 16 batch rows/block.
//  - Cost model from r2/r4 counters (32 active CUs): step = MFMA issue (~2483
//    cy: 128 x 16x16x32 @19.4cy/SIMD) + VALU (~3050) + barrier, phases SERIAL.
//  - This round: K=128 fp8 MFMA (v_mfma_f32_16x16x128_f8f6f4, raw asm,
//    cbsz=blgp=0 -> fp8/fp8) halves+ the MFMA phase (32 x 34.5 = 1104 cy).
//    Weights: 8 frags/wave in regs (64 VGPRs), 8 in LDS (128 KB as split 16B
//    halves, 2-way-bank-free) -> pressure ~158 regs, no spill risk, no AGPR
//    pin copies (round-4's per-iter "+v" pin cost ~192 copies/wave/step).
//  - raw s_barrier with lgkmcnt-only wait keeps xg prefetch in flight.

typedef unsigned short u16;
typedef __bf16 bf16x8 __attribute__((ext_vector_type(8)));
typedef float  f32x4  __attribute__((ext_vector_type(4)));
typedef int    i32x4v __attribute__((ext_vector_type(4)));
typedef int    i32x8v __attribute__((ext_vector_type(8)));

#define B_    512
#define L_    200
#define EMB_  128
#define TDIM_ 10
#define IN_   138
#define INP_  160   // feat padded K (5 x 32)
#define H_    256
#define G4_   1024
#define T_    200
#define DS_   (1.0f/1024.0f)   // descale: (W*64)*(h*16), xg prescaled *1024
#define LOG2E 1.4426950408889634f
#define EXP2(x) __builtin_amdgcn_exp2f(x)

static __device__ __forceinline__ float bf2f(u16 u) {
  union { uint32_t i; float f; } v; v.i = ((uint32_t)u) << 16; return v.f;
}
static __device__ __forceinline__ u16 f2bf(float f) {
  __bf16 h = (__bf16)f; return __builtin_bit_cast(u16, h);
}
static __device__ __forceinline__ float bflo(uint32_t u) {
  return __builtin_bit_cast(float, (uint32_t)(u << 16));
}
static __device__ __forceinline__ float bfhi(uint32_t u) {
  return __builtin_bit_cast(float, (uint32_t)(u & 0xffff0000u));
}
static __device__ __forceinline__ float sigf(float x) {
  return __builtin_amdgcn_rcpf(1.0f + EXP2(-x * LOG2E));
}
static __device__ __forceinline__ float tanh_(float x) {
  x = fminf(fmaxf(x, -15.f), 15.f);
  float e = EXP2(2.0f * LOG2E * x);
  return (e - 1.0f) * __builtin_amdgcn_rcpf(e + 1.0f);
}
static __device__ __forceinline__ f32x4 mfma16(bf16x8 a, bf16x8 b, f32x4 c) {
  return __builtin_amdgcn_mfma_f32_16x16x32_bf16(a, b, c, 0, 0, 0);
}
static __device__ __forceinline__ f32x4 vzero4() {
  f32x4 v; v[0] = 0.f; v[1] = 0.f; v[2] = 0.f; v[3] = 0.f; return v;
}

// ---------------- K1: s[b] = sum_l t^2 ----------------
__global__ void k_norm(const int* __restrict__ x, float* __restrict__ s) {
  int b = blockIdx.x;
  int tid = threadIdx.x;
  float v = 0.f;
  if (tid < L_) {
    float t = (float)x[(b * L_ + tid) * 2];
    v = t * t;
  }
  #pragma unroll
  for (int o = 32; o; o >>= 1) v += __shfl_down(v, o);
  __shared__ float p[4];
  if ((tid & 63) == 0) p[tid >> 6] = v;
  __syncthreads();
  if (tid == 0) s[b] = p[0] + p[1] + p[2] + p[3];
}

// ---------------- K0b: W_hh fp32 -> K=128 MX A-frags, fp8 e4m3 *64 ---------
// frag fs = w*16 + tt*2 + kp2; dword idx = (fs*64 + lane)*8 + d.
// lane (q=lane>>4, mm=lane&15) holds A[g][k]: g=(w+8tt)*16+mm,
// k = kp2*128 + q*32 + d*4 + byte   (K=128 family layout: 32 contig k/lane)
__global__ void k_prep_mx(const float* __restrict__ whh, int* __restrict__ wf8) {
  int idx = blockIdx.x * blockDim.x + threadIdx.x;  // < 65536 dwords
  int d = idx & 7;
  int lane = (idx >> 3) & 63;
  int fs = idx >> 9;
  int kp2 = fs & 1, tt = (fs >> 1) & 7, w = fs >> 4;
  int mm = lane & 15, q = lane >> 4;
  int g = (w + 8 * tt) * 16 + mm;
  int k = kp2 * 128 + q * 32 + d * 4;
  const float* src = whh + g * 256 + k;
  int v = __builtin_amdgcn_cvt_pk_fp8_f32(src[0] * 64.f, src[1] * 64.f, 0, false);
  v     = __builtin_amdgcn_cvt_pk_fp8_f32(src[2] * 64.f, src[3] * 64.f, v, true);
  wf8[idx] = v;
}

// ---------------- K2: features (t_emb normalized | l_emb | pad) bf16 --------
__global__ void k_feat(const int* __restrict__ x, const float* __restrict__ emb,
                       const float* __restrict__ tsW, const float* __restrict__ s,
                       u16* __restrict__ feat) {
  int idx = blockIdx.x * blockDim.x + threadIdx.x;
  if (idx >= B_ * L_ * INP_) return;
  int c = idx % INP_;
  int row = idx / INP_;
  int b = row / L_;
  float v = 0.f;
  if (c < TDIM_) {
    float t = (float)x[row * 2 + 0];
    float wd = tsW[c];
    float den = fmaxf(fabsf(wd) * sqrtf(s[b]), 1e-12f);
    v = t * wd / den;
  } else if (c < IN_) {
    int id = x[row * 2 + 1];
    int idc = id < 0 ? 0 : id;
    float e = emb[(long)idc * EMB_ + (c - TDIM_)];
    v = (id >= 0) ? e : 0.f;
  }
  feat[idx] = f2bf(v);
}

// ---------------- K3: xg = (feat @ W_ih^T + b_ih + b_hh) * 1024, bf16 -------
__global__ __launch_bounds__(512) void k_xg(
    const u16* __restrict__ feat, const float* __restrict__ wih,
    const float* __restrict__ bih, const float* __restrict__ bhh,
    u16* __restrict__ xg) {
  __shared__ u16 Bs[256 * 176];  // 90112 B; reused as 128x264 out-tile
  const int nt = blockIdx.x;   // 0..3
  const int mt = blockIdx.y;   // 0..799
  const int tid = threadIdx.x;
  const int w = tid >> 6, lane = tid & 63;
  const int q = lane >> 4, nm = lane & 15;
  for (int i2 = tid; i2 < 256 * 88; i2 += 512) {
    int gl = i2 / 88, f2 = (i2 % 88) * 2;
    int pk = 0;
    if (f2 < IN_) {
      float2 v = *(const float2*)(wih + (long)(nt * 256 + gl) * IN_ + f2);
      pk = (int)f2bf(v.x) | ((int)f2bf(v.y) << 16);
    }
    *(int*)&Bs[gl * 176 + f2] = pk;
  }
  float bias[16];
  #pragma unroll
  for (int nu = 0; nu < 16; ++nu) {
    int g = nt * 256 + nu * 16 + nm;
    bias[nu] = bih[g] + bhh[g];
  }
  __syncthreads();
  f32x4 acc[16];
  #pragma unroll
  for (int nu = 0; nu < 16; ++nu) acc[nu] = vzero4();
  const u16* arow = feat + (long)(mt * 128 + w * 16) * INP_;
  #pragma unroll
  for (int kp = 0; kp < 5; ++kp) {
    bf16x8 a = *(const bf16x8*)(arow + (nm * INP_ + kp * 32 + q * 8));
    #pragma unroll
    for (int nu = 0; nu < 16; ++nu) {
      bf16x8 bb = *(const bf16x8*)&Bs[(nu * 16 + nm) * 176 + kp * 32 + q * 8];
      acc[nu] = mfma16(a, bb, acc[nu]);
    }
  }
  __syncthreads();
  u16* Os = Bs;
  #pragma unroll
  for (int nu = 0; nu < 16; ++nu) {
    #pragma unroll
    for (int r = 0; r < 4; ++r) {
      int row = w * 16 + 4 * q + r;
      Os[row * 264 + nu * 16 + nm] = f2bf((acc[nu][r] + bias[nu]) * 1024.f);
    }
  }
  __syncthreads();
  #pragma unroll
  for (int it = 0; it < 8; ++it) {
    int flat = it * 512 + tid;
    int row = flat >> 5, c = flat & 31;
    uint4 v = *(const uint4*)&Os[row * 264 + c * 8];
    *(uint4*)&xg[(long)(mt * 128 + row) * G4_ + nt * 256 + c * 8] = v;
  }
}

// ---------------- K4: forward LSTM scan, K=128 fp8 MFMA ----------------
// Wave w owns m-tiles {w+8*tt}: tt {0,1}=i {2,3}=f {4,5}=g {6,7}=o.
// 2 MFMAs per acc chain (kp2=0: k 0..127, kp2=1: k 128..255).
#define MX2(accv, A0, A1, B0, B1) \
  asm volatile("v_mfma_f32_16x16x128_f8f6f4 %0, %1, %3, %0\n\t" \
               "v_mfma_f32_16x16x128_f8f6f4 %0, %2, %4, %0" \
               : "+v"(accv) : "v"(A0), "v"(A1), "v"(B0), "v"(B1));
#define AINIT(i) \
  f32x4 acc##i; acc##i[0] = bflo(pf##i.x); acc##i[1] = bfhi(pf##i.x); \
  acc##i[2] = bflo(pf##i.y); acc##i[3] = bfhi(pf##i.y);
#define PFL(i) pf##i = *(const uint2*)(xn + ((w + 8 * (i)) * 16 + 4 * q));
#define ALDS(f) __builtin_shufflevector(ldsX[(w * 8 + (f)) * 64 + lane], \
                                        ldsY[(w * 8 + (f)) * 64 + lane], \
                                        0, 1, 2, 3, 4, 5, 6, 7)
#define EPI(jj, aI, aF, aG, aO, cs) { \
  f32x4 hv; \
  _Pragma("unroll") \
  for (int r = 0; r < 4; ++r) { \
    float si = __builtin_amdgcn_rcpf(1.f + EXP2(aI[r] * c_sig)); \
    float sf = __builtin_amdgcn_rcpf(1.f + EXP2(aF[r] * c_sig)); \
    float so = __builtin_amdgcn_rcpf(1.f + EXP2(aO[r] * c_sig)); \
    float tg = 1.f - 2.f * __builtin_amdgcn_rcpf(1.f + EXP2(aG[r] * c_tg)); \
    float c = sf * cs[r] + si * tg; \
    float tc = 1.f - 2.f * __builtin_amdgcn_rcpf(1.f + EXP2(c * c_tc)); \
    cs[r] = c; hv[r] = so * tc; \
  } \
  int pk = __builtin_amdgcn_cvt_pk_fp8_f32(hv[0] * 16.f, hv[1] * 16.f, 0, false); \
  pk     = __builtin_amdgcn_cvt_pk_fp8_f32(hv[2] * 16.f, hv[3] * 16.f, pk, true); \
  hw[nn * 68 + 4 * w + 32 * (jj) + q] = pk; \
  if (t == T_ - 1) *(f32x4*)&hf[(long)b * H_ + 16 * w + 128 * (jj) + 4 * q] = hv; }

__global__ __launch_bounds__(512, 2) void k_lstm_f(
    const int* __restrict__ wf8, const u16* __restrict__ xg,
    float* __restrict__ hf) {
  __shared__ i32x4v ldsX[64 * 64];  // 65536 B: frag dwords 0-3 (tt 0..3)
  __shared__ i32x4v ldsY[64 * 64];  // 65536 B: frag dwords 4-7
  __shared__ int hls[2][16 * 68];   // 8704 B: fp8 h, stride 272 B, dbuf
  const int tid = threadIdx.x;
  const int w = tid >> 6;
  const int lane = tid & 63;
  const int q = lane >> 4;
  const int nn = lane & 15;
  const int b = blockIdx.x * 16 + nn;
  const float c_sig = -DS_ * LOG2E;
  const float c_tg  = 2.f * DS_ * LOG2E;
  const float c_tc  = 2.f * LOG2E;

#define WREG(fi) (*(const i32x8v*)(wf8 + (long)((w * 16 + (fi)) * 64 + lane) * 8))
  // reg-resident A-frags: tt = 4..7 (gates g,o) — 64 VGPRs
  i32x8v W40 = WREG(8),  W41 = WREG(9),  W50 = WREG(10), W51 = WREG(11);
  i32x8v W60 = WREG(12), W61 = WREG(13), W70 = WREG(14), W71 = WREG(15);
  // LDS-resident A-frags: tt = 0..3 (gates i,f) — 128 KB, split 16B halves
  #pragma unroll
  for (int f = 0; f < 8; ++f) {
    i32x8v v = WREG(f);
    ldsX[(w * 8 + f) * 64 + lane] = __builtin_shufflevector(v, v, 0, 1, 2, 3);
    ldsY[(w * 8 + f) * 64 + lane] = __builtin_shufflevector(v, v, 4, 5, 6, 7);
  }
  for (int i = tid; i < 16 * 68; i += 512) hls[0][i] = 0;

  const u16* xgb = xg + (long)b * (L_ * G4_);
  uint2 pf0, pf1, pf2, pf3, pf4, pf5, pf6, pf7;
  {
    const u16* xn = xgb;
    PFL(0) PFL(1) PFL(2) PFL(3) PFL(4) PFL(5) PFL(6) PFL(7)
  }
  f32x4 cst0 = vzero4(), cst1 = vzero4();
  __syncthreads();

  #pragma unroll 1
  for (int t = 0; t < T_; ++t) {
    AINIT(0) AINIT(1) AINIT(2) AINIT(3) AINIT(4) AINIT(5) AINIT(6) AINIT(7)
    // next step's xg prefetch; barrier below is lgkm-only so it stays in flight
    {
      const u16* xn = xgb + (long)(t + 1 < T_ ? t + 1 : t) * G4_;
      PFL(0) PFL(1) PFL(2) PFL(3) PFL(4) PFL(5) PFL(6) PFL(7)
    }
    const int* hr = hls[t & 1];
    // B-frags: lane(q,nn): k = kp2*128 + q*32 + byte of row nn
    i32x8v B0 = __builtin_shufflevector(
        *(const i32x4v*)&hr[nn * 68 + q * 8],
        *(const i32x4v*)&hr[nn * 68 + q * 8 + 4], 0, 1, 2, 3, 4, 5, 6, 7);
    i32x8v B1 = __builtin_shufflevector(
        *(const i32x4v*)&hr[nn * 68 + 32 + q * 8],
        *(const i32x4v*)&hr[nn * 68 + 32 + q * 8 + 4], 0, 1, 2, 3, 4, 5, 6, 7);
    {
      i32x8v A0, A1;
      A0 = ALDS(0); A1 = ALDS(1); MX2(acc0, A0, A1, B0, B1);
      A0 = ALDS(2); A1 = ALDS(3); MX2(acc1, A0, A1, B0, B1);
      A0 = ALDS(4); A1 = ALDS(5); MX2(acc2, A0, A1, B0, B1);
      A0 = ALDS(6); A1 = ALDS(7); MX2(acc3, A0, A1, B0, B1);
    }
    MX2(acc4, W40, W41, B0, B1);
    MX2(acc5, W50, W51, B0, B1);
    MX2(acc6, W60, W61, B0, B1);
    MX2(acc7, W70, W71, B0, B1);
    // MFMA->VALU read hazard cover for the youngest accs
    asm volatile("s_nop 7\n\ts_nop 7"
                 : "+v"(acc4), "+v"(acc5), "+v"(acc6), "+v"(acc7));
    int* hw = hls[1 - (t & 1)];
    EPI(0, acc0, acc2, acc4, acc6, cst0)
    EPI(1, acc1, acc3, acc5, acc7, cst1)
    // raw barrier: wait DS only (lgkmcnt(0)); vmcnt prefetch NOT drained.
    __asm__ volatile("" ::: "memory");
    __builtin_amdgcn_s_waitcnt(0xc07f);
    __builtin_amdgcn_s_barrier();
    __asm__ volatile("" ::: "memory");
  }
}

// ---------------- K5: backward LSTM = ONE step from zero state at l=L-1 -----
__global__ __launch_bounds__(256) void k_bwd(
    const u16* __restrict__ feat, const float* __restrict__ wih,
    const float* __restrict__ bih, const float* __restrict__ bhh,
    float* __restrict__ hb) {
  const int b0 = blockIdx.x * 8;
  const int tid = threadIdx.x;
  __shared__ float fv[8][IN_];
  for (int i = tid; i < 8 * IN_; i += 256) {
    int r = i / IN_, c = i % IN_;
    fv[r][c] = bf2f(feat[((long)(b0 + r) * L_ + (L_ - 1)) * INP_ + c]);
  }
  __syncthreads();
  float gi[8], gg[8], go[8];
  float bi_ = bih[tid] + bhh[tid];
  float bg_ = bih[2 * H_ + tid] + bhh[2 * H_ + tid];
  float bo_ = bih[3 * H_ + tid] + bhh[3 * H_ + tid];
  #pragma unroll
  for (int r = 0; r < 8; ++r) { gi[r] = bi_; gg[r] = bg_; go[r] = bo_; }
  const float* wi_ = wih + (long)tid * IN_;
  const float* wg_ = wih + (long)(2 * H_ + tid) * IN_;
  const float* wo_ = wih + (long)(3 * H_ + tid) * IN_;
  for (int f = 0; f < IN_; ++f) {
    float a = wi_[f], gc = wg_[f], oc = wo_[f];
    #pragma unroll
    for (int r = 0; r < 8; ++r) {
      float x = fv[r][f];
      gi[r] += a * x;
      gg[r] += gc * x;
      go[r] += oc * x;
    }
  }
  #pragma unroll
  for (int r = 0; r < 8; ++r) {
    float c = sigf(gi[r]) * tanh_(gg[r]);
    hb[(long)(b0 + r) * H_ + tid] = sigf(go[r]) * tanh_(c);
  }
}

// ---------------- K6: fc head ----------------
__global__ void k_fc(const float* __restrict__ hf, const float* __restrict__ hb,
                     const float* __restrict__ fcw, const float* __restrict__ fcb,
                     float* __restrict__ out) {
  int b = blockIdx.x;
  int lane = threadIdx.x;  // 64
  float p0 = 0.f, p1 = 0.f;
  #pragma unroll
  for (int k = lane; k < 2 * H_; k += 64) {
    float v = (k < H_) ? hf[b * H_ + k] : hb[b * H_ + (k - H_)];
    p0 += v * fcw[k];
    p1 += v * fcw[2 * H_ + k];
  }
  #pragma unroll
  for (int o = 32; o; o >>= 1) {
    p0 += __shfl_down(p0, o);
    p1 += __shfl_down(p1, o);
  }
  if (lane == 0) {
    out[b * 2 + 0] = p0 + fcb[0];
    out[b * 2 + 1] = p1 + fcb[1];
  }
}

extern "C" void kernel_launch(void* const* d_in, const int* in_sizes, int n_in,
                              void* d_out, int out_size, void* d_ws, size_t ws_size,
                              hipStream_t stream) {
  const int*   x    = (const int*)  d_in[0];
  const float* emb  = (const float*)d_in[1];
  const float* tsW  = (const float*)d_in[2];
  const float* wihf = (const float*)d_in[3];
  const float* whhf = (const float*)d_in[4];
  const float* bihf = (const float*)d_in[5];
  const float* bhhf = (const float*)d_in[6];
  const float* wihb = (const float*)d_in[7];
  // d_in[8] = w_hh_b: unused (one backward step from zero state)
  const float* bihb = (const float*)d_in[9];
  const float* bhhb = (const float*)d_in[10];
  const float* fcw  = (const float*)d_in[11];
  const float* fcb  = (const float*)d_in[12];
  float* out = (float*)d_out;

  // workspace layout (243,795,968 bytes total — proven to fit)
  char* ws = (char*)d_ws;
  float* s    = (float*)(ws);                  //       2,048
  int*   wf8  = (int*)  (ws + 2048);           //     262,144 (MX fp8 W frags)
  u16*   feat = (u16*)  (ws + 264192);         //  32,768,000
  u16*   xg   = (u16*)  (ws + 33032192);       // 209,715,200
  float* hf   = (float*)(ws + 242747392);      //     524,288
  float* hb   = (float*)(ws + 243271680);      //     524,288

  k_norm   <<<dim3(512),     dim3(256), 0, stream>>>(x, s);
  k_prep_mx<<<dim3(256),     dim3(256), 0, stream>>>(whhf, wf8);
  k_feat   <<<dim3(64000),   dim3(256), 0, stream>>>(x, emb, tsW, s, feat);
  k_xg     <<<dim3(4, 800),  dim3(512), 0, stream>>>(feat, wihf, bihf, bhhf, xg);
  k_lstm_f <<<dim3(32),      dim3(512), 0, stream>>>(wf8, xg, hf);
  k_bwd    <<<dim3(64),      dim3(256), 0, stream>>>(feat, wihb, bihb, bhhb, hb);
  k_fc     <<<dim3(512),     dim3(64),  0, stream>>>(hf, hb, fcw, fcb, out);
}

// Round 6
// 798.810 us; speedup vs baseline: 1.2866x; 1.0068x over previous
//
#include <hip/hip_runtime.h>
#include <stdint.h>

// BiRNN on MI355X — round 6.
//  - backward LSTM = ONE step from zero state (only out[:, -1] consumed).
//  - forward scan: persistent 32 blocks x 512 thr, 16 batch rows/block.
//  - Round-5 autopsy: half of W in LDS cost ~1900 cy/step on the shared LDS
//    pipe (128 ds_read_b128/CU/step). gfx950 MFMA reads A from AGPRs: hold
//    ALL 16 K=128 fp8 W-frags/wave (128 regs) in AGPRs via "a" asm
//    constraints. LDS now only the 8.7 KB h double-buffer.
//  - Epilogue: rcp-fused gates (8 trans/update, Inf-safe via exp2-arg clamp),
//    j=1 MFMA chains interleaved with j=0 epilogue rows (pipe overlap).
//  - raw s_barrier with lgkmcnt-only wait keeps xg prefetch in flight.

typedef unsigned short u16;
typedef __bf16 bf16x8 __attribute__((ext_vector_type(8)));
typedef float  f32x4  __attribute__((ext_vector_type(4)));
typedef int    i32x4v __attribute__((ext_vector_type(4)));
typedef int    i32x8v __attribute__((ext_vector_type(8)));

#define B_    512
#define L_    200
#define EMB_  128
#define TDIM_ 10
#define IN_   138
#define INP_  160   // feat padded K (5 x 32)
#define H_    256
#define G4_   1024
#define T_    200
#define DS_   (1.0f/1024.0f)   // descale: (W*64)*(h*16), xg prescaled *1024
#define LOG2E 1.4426950408889634f
#define EXP2(x) __builtin_amdgcn_exp2f(x)

static __device__ __forceinline__ float bf2f(u16 u) {
  union { uint32_t i; float f; } v; v.i = ((uint32_t)u) << 16; return v.f;
}
static __device__ __forceinline__ u16 f2bf(float f) {
  __bf16 h = (__bf16)f; return __builtin_bit_cast(u16, h);
}
static __device__ __forceinline__ float bflo(uint32_t u) {
  return __builtin_bit_cast(float, (uint32_t)(u << 16));
}
static __device__ __forceinline__ float bfhi(uint32_t u) {
  return __builtin_bit_cast(float, (uint32_t)(u & 0xffff0000u));
}
static __device__ __forceinline__ float sigf(float x) {
  return __builtin_amdgcn_rcpf(1.0f + EXP2(-x * LOG2E));
}
static __device__ __forceinline__ float tanh_(float x) {
  x = fminf(fmaxf(x, -15.f), 15.f);
  float e = EXP2(2.0f * LOG2E * x);
  return (e - 1.0f) * __builtin_amdgcn_rcpf(e + 1.0f);
}
static __device__ __forceinline__ f32x4 mfma16(bf16x8 a, bf16x8 b, f32x4 c) {
  return __builtin_amdgcn_mfma_f32_16x16x32_bf16(a, b, c, 0, 0, 0);
}
static __device__ __forceinline__ f32x4 vzero4() {
  f32x4 v; v[0] = 0.f; v[1] = 0.f; v[2] = 0.f; v[3] = 0.f; return v;
}

// ---------------- K1: s[b] = sum_l t^2 ----------------
__global__ void k_norm(const int* __restrict__ x, float* __restrict__ s) {
  int b = blockIdx.x;
  int tid = threadIdx.x;
  float v = 0.f;
  if (tid < L_) {
    float t = (float)x[(b * L_ + tid) * 2];
    v = t * t;
  }
  #pragma unroll
  for (int o = 32; o; o >>= 1) v += __shfl_down(v, o);
  __shared__ float p[4];
  if ((tid & 63) == 0) p[tid >> 6] = v;
  __syncthreads();
  if (tid == 0) s[b] = p[0] + p[1] + p[2] + p[3];
}

// ---------------- K0b: W_hh fp32 -> K=128 MX A-frags, fp8 e4m3 *64 ---------
// frag fs = w*16 + tt*2 + kp2; dword idx = (fs*64 + lane)*8 + d.
// lane (q=lane>>4, mm=lane&15) holds A[g][k]: g=(w+8tt)*16+mm,
// k = kp2*128 + q*32 + d*4 + byte   (verified by r4->r5 bit-identical absmax)
__global__ void k_prep_mx(const float* __restrict__ whh, int* __restrict__ wf8) {
  int idx = blockIdx.x * blockDim.x + threadIdx.x;  // < 65536 dwords
  int d = idx & 7;
  int lane = (idx >> 3) & 63;
  int fs = idx >> 9;
  int kp2 = fs & 1, tt = (fs >> 1) & 7, w = fs >> 4;
  int mm = lane & 15, q = lane >> 4;
  int g = (w + 8 * tt) * 16 + mm;
  int k = kp2 * 128 + q * 32 + d * 4;
  const float* src = whh + g * 256 + k;
  int v = __builtin_amdgcn_cvt_pk_fp8_f32(src[0] * 64.f, src[1] * 64.f, 0, false);
  v     = __builtin_amdgcn_cvt_pk_fp8_f32(src[2] * 64.f, src[3] * 64.f, v, true);
  wf8[idx] = v;
}

// ---------------- K2: features (t_emb normalized | l_emb | pad) bf16 --------
__global__ void k_feat(const int* __restrict__ x, const float* __restrict__ emb,
                       const float* __restrict__ tsW, const float* __restrict__ s,
                       u16* __restrict__ feat) {
  int idx = blockIdx.x * blockDim.x + threadIdx.x;
  if (idx >= B_ * L_ * INP_) return;
  int c = idx % INP_;
  int row = idx / INP_;
  int b = row / L_;
  float v = 0.f;
  if (c < TDIM_) {
    float t = (float)x[row * 2 + 0];
    float wd = tsW[c];
    float den = fmaxf(fabsf(wd) * sqrtf(s[b]), 1e-12f);
    v = t * wd / den;
  } else if (c < IN_) {
    int id = x[row * 2 + 1];
    int idc = id < 0 ? 0 : id;
    float e = emb[(long)idc * EMB_ + (c - TDIM_)];
    v = (id >= 0) ? e : 0.f;
  }
  feat[idx] = f2bf(v);
}

// ---------------- K3: xg = (feat @ W_ih^T + b_ih + b_hh) * 1024, bf16 -------
// M-tile 256 x N-tile 256, grid (4, 400): halves W staging and per-MFMA
// ds_reads vs round 5. Out-tile transposed through LDS in 2 passes of 128.
__global__ __launch_bounds__(512, 2) void k_xg(
    const u16* __restrict__ feat, const float* __restrict__ wih,
    const float* __restrict__ bih, const float* __restrict__ bhh,
    u16* __restrict__ xg) {
  __shared__ u16 Bs[256 * 176];  // 90112 B; reused as 128x264 out-tile
  const int nt = blockIdx.x;   // 0..3
  const int mt = blockIdx.y;   // 0..399
  const int tid = threadIdx.x;
  const int w = tid >> 6, lane = tid & 63;
  const int q = lane >> 4, nm = lane & 15;
  for (int i2 = tid; i2 < 256 * 88; i2 += 512) {
    int gl = i2 / 88, f2 = (i2 % 88) * 2;
    int pk = 0;
    if (f2 < IN_) {
      float2 v = *(const float2*)(wih + (long)(nt * 256 + gl) * IN_ + f2);
      pk = (int)f2bf(v.x) | ((int)f2bf(v.y) << 16);
    }
    *(int*)&Bs[gl * 176 + f2] = pk;
  }
  float bias[16];
  #pragma unroll
  for (int nu = 0; nu < 16; ++nu) {
    int g = nt * 256 + nu * 16 + nm;
    bias[nu] = bih[g] + bhh[g];
  }
  __syncthreads();
  f32x4 acc[2][16];
  #pragma unroll
  for (int m = 0; m < 2; ++m)
    #pragma unroll
    for (int nu = 0; nu < 16; ++nu) acc[m][nu] = vzero4();
  const u16* arow = feat + (long)(mt * 256 + w * 32) * INP_;
  #pragma unroll
  for (int kp = 0; kp < 5; ++kp) {
    bf16x8 a0 = *(const bf16x8*)(arow + (nm * INP_ + kp * 32 + q * 8));
    bf16x8 a1 = *(const bf16x8*)(arow + ((16 + nm) * INP_ + kp * 32 + q * 8));
    #pragma unroll
    for (int nu = 0; nu < 16; ++nu) {
      bf16x8 bb = *(const bf16x8*)&Bs[(nu * 16 + nm) * 176 + kp * 32 + q * 8];
      acc[0][nu] = mfma16(a0, bb, acc[0][nu]);
      acc[1][nu] = mfma16(a1, bb, acc[1][nu]);
    }
  }
  u16* Os = Bs;  // [128 rows][264 cols]
  #pragma unroll
  for (int p = 0; p < 2; ++p) {
    __syncthreads();
    if ((w >> 2) == p) {
      #pragma unroll
      for (int nu = 0; nu < 16; ++nu)
        #pragma unroll
        for (int m = 0; m < 2; ++m)
          #pragma unroll
          for (int r = 0; r < 4; ++r) {
            int row = (w & 3) * 32 + m * 16 + 4 * q + r;
            Os[row * 264 + nu * 16 + nm] = f2bf((acc[m][nu][r] + bias[nu]) * 1024.f);
          }
    }
    __syncthreads();
    #pragma unroll
    for (int it = 0; it < 8; ++it) {
      int flat = it * 512 + tid;
      int row = flat >> 5, c = flat & 31;
      uint4 v = *(const uint4*)&Os[row * 264 + c * 8];
      *(uint4*)&xg[(long)(mt * 256 + p * 128 + row) * G4_ + nt * 256 + c * 8] = v;
    }
  }
}

// ---------------- K4: forward LSTM scan, all-AGPR K=128 fp8 MFMA ------------
// Wave w owns m-tiles {w+8*tt}: tt {0,1}=i {2,3}=f {4,5}=g {6,7}=o.
// All 16 W-frags/wave in AGPRs ("a" asm constraints); LDS = h dbuf only.
#define MX2A(accv, A0, A1, Bx, By) \
  asm volatile("v_mfma_f32_16x16x128_f8f6f4 %0, %1, %3, %0\n\t" \
               "v_mfma_f32_16x16x128_f8f6f4 %0, %2, %4, %0" \
               : "+v"(accv) : "a"(A0), "a"(A1), "v"(Bx), "v"(By));
#define AINIT(i) \
  f32x4 acc##i; acc##i[0] = bflo(pf##i.x); acc##i[1] = bfhi(pf##i.x); \
  acc##i[2] = bflo(pf##i.y); acc##i[3] = bfhi(pf##i.y);
#define PFL(i) pf##i = *(const uint2*)(xn + ((w + 8 * (i)) * 16 + 4 * q));
// rcp-fused gates: si*tg = (e^{2g}-1) * rcp((1+e^{-i})(1+e^{2g})); Inf-safe
// via exp2-arg clamp (<=126) and graceful rcp(Inf)=0 elsewhere.
#define EPIROW(r, cs, aI, aF, aG, aO, hv) { \
  float ei = EXP2((aI)[r] * c_sig); \
  float ef = EXP2((aF)[r] * c_sig); \
  float eo = EXP2((aO)[r] * c_sig); \
  float eg = EXP2(fminf((aG)[r] * c_tg, 126.f)); \
  float c  = cs[r] * __builtin_amdgcn_rcpf(1.f + ef) \
           + (eg - 1.f) * __builtin_amdgcn_rcpf((1.f + ei) * (1.f + eg)); \
  cs[r] = c; \
  float ec = EXP2(fminf(c * c_tc, 126.f)); \
  (hv)[r] = (ec - 1.f) * __builtin_amdgcn_rcpf((1.f + eo) * (1.f + ec)); }
#define HPACK(jj, hv) { \
  int pk = __builtin_amdgcn_cvt_pk_fp8_f32((hv)[0] * 16.f, (hv)[1] * 16.f, 0, false); \
  pk     = __builtin_amdgcn_cvt_pk_fp8_f32((hv)[2] * 16.f, (hv)[3] * 16.f, pk, true); \
  hw[nn * 68 + 4 * w + 32 * (jj) + q] = pk; \
  if (t == T_ - 1) *(f32x4*)&hf[(long)b * H_ + 16 * w + 128 * (jj) + 4 * q] = (hv); }

__global__ __launch_bounds__(512, 2) void k_lstm_f(
    const int* __restrict__ wf8, const u16* __restrict__ xg,
    float* __restrict__ hf) {
  __shared__ int hls[2][16 * 68];   // 8704 B: fp8 h, stride 272 B, dbuf
  const int tid = threadIdx.x;
  const int w = tid >> 6;
  const int lane = tid & 63;
  const int q = lane >> 4;
  const int nn = lane & 15;
  const int b = blockIdx.x * 16 + nn;
  const float c_sig = -DS_ * LOG2E;
  const float c_tg  = 2.f * DS_ * LOG2E;
  const float c_tc  = 2.f * LOG2E;

#define WREG(fi) (*(const i32x8v*)(wf8 + (long)((w * 16 + (fi)) * 64 + lane) * 8))
  // all 16 A-frags -> register file ("a" uses below put them in AGPRs)
  i32x8v W00 = WREG(0),  W01 = WREG(1),  W10 = WREG(2),  W11 = WREG(3);
  i32x8v W20 = WREG(4),  W21 = WREG(5),  W30 = WREG(6),  W31 = WREG(7);
  i32x8v W40 = WREG(8),  W41 = WREG(9),  W50 = WREG(10), W51 = WREG(11);
  i32x8v W60 = WREG(12), W61 = WREG(13), W70 = WREG(14), W71 = WREG(15);
  for (int i = tid; i < 16 * 68; i += 512) hls[0][i] = 0;

  const u16* xgb = xg + (long)b * (L_ * G4_);
  uint2 pf0, pf1, pf2, pf3, pf4, pf5, pf6, pf7;
  {
    const u16* xn = xgb;
    PFL(0) PFL(1) PFL(2) PFL(3) PFL(4) PFL(5) PFL(6) PFL(7)
  }
  f32x4 cst0 = vzero4(), cst1 = vzero4();
  __syncthreads();

  #pragma unroll 1
  for (int t = 0; t < T_; ++t) {
    AINIT(0) AINIT(1) AINIT(2) AINIT(3) AINIT(4) AINIT(5) AINIT(6) AINIT(7)
    // next step's xg prefetch; barrier below is lgkm-only so it stays in flight
    {
      const u16* xn = xgb + (long)(t + 1 < T_ ? t + 1 : t) * G4_;
      PFL(0) PFL(1) PFL(2) PFL(3) PFL(4) PFL(5) PFL(6) PFL(7)
    }
    const int* hr = hls[t & 1];
    // B-frags: lane(q,nn): k = kp2*128 + q*32 + byte of row nn
    i32x8v B0 = __builtin_shufflevector(
        *(const i32x4v*)&hr[nn * 68 + q * 8],
        *(const i32x4v*)&hr[nn * 68 + q * 8 + 4], 0, 1, 2, 3, 4, 5, 6, 7);
    i32x8v B1 = __builtin_shufflevector(
        *(const i32x4v*)&hr[nn * 68 + 32 + q * 8],
        *(const i32x4v*)&hr[nn * 68 + 32 + q * 8 + 4], 0, 1, 2, 3, 4, 5, 6, 7);
    MX2A(acc0, W00, W01, B0, B1);
    MX2A(acc2, W20, W21, B0, B1);
    MX2A(acc4, W40, W41, B0, B1);
    MX2A(acc6, W60, W61, B0, B1);
    MX2A(acc1, W10, W11, B0, B1);
    MX2A(acc3, W30, W31, B0, B1);
    // hazard cover before VALU reads of j=0 accs
    asm volatile("s_nop 7\n\ts_nop 7"
                 : "+v"(acc0), "+v"(acc2), "+v"(acc4), "+v"(acc6));
    int* hw = hls[1 - (t & 1)];
    f32x4 hv0;
    // interleave j=0 epilogue rows (trans pipe) with j=1 MFMAs (matrix pipe)
    EPIROW(0, cst0, acc0, acc2, acc4, acc6, hv0)
    MX2A(acc5, W50, W51, B0, B1);
    EPIROW(1, cst0, acc0, acc2, acc4, acc6, hv0)
    MX2A(acc7, W70, W71, B0, B1);
    EPIROW(2, cst0, acc0, acc2, acc4, acc6, hv0)
    EPIROW(3, cst0, acc0, acc2, acc4, acc6, hv0)
    HPACK(0, hv0)
    asm volatile("s_nop 7\n\ts_nop 7"
                 : "+v"(acc1), "+v"(acc3), "+v"(acc5), "+v"(acc7));
    f32x4 hv1;
    EPIROW(0, cst1, acc1, acc3, acc5, acc7, hv1)
    EPIROW(1, cst1, acc1, acc3, acc5, acc7, hv1)
    EPIROW(2, cst1, acc1, acc3, acc5, acc7, hv1)
    EPIROW(3, cst1, acc1, acc3, acc5, acc7, hv1)
    HPACK(1, hv1)
    // raw barrier: wait DS only (lgkmcnt(0)); vmcnt prefetch NOT drained.
    __asm__ volatile("" ::: "memory");
    __builtin_amdgcn_s_waitcnt(0xc07f);
    __builtin_amdgcn_s_barrier();
    __asm__ volatile("" ::: "memory");
  }
}

// ---------------- K5: backward LSTM = ONE step from zero state at l=L-1 -----
__global__ __launch_bounds__(256) void k_bwd(
    const u16* __restrict__ feat, const float* __restrict__ wih,
    const float* __restrict__ bih, const float* __restrict__ bhh,
    float* __restrict__ hb) {
  const int b0 = blockIdx.x * 8;
  const int tid = threadIdx.x;
  __shared__ float fv[8][IN_];
  for (int i = tid; i < 8 * IN_; i += 256) {
    int r = i / IN_, c = i % IN_;
    fv[r][c] = bf2f(feat[((long)(b0 + r) * L_ + (L_ - 1)) * INP_ + c]);
  }
  __syncthreads();
  float gi[8], gg[8], go[8];
  float bi_ = bih[tid] + bhh[tid];
  float bg_ = bih[2 * H_ + tid] + bhh[2 * H_ + tid];
  float bo_ = bih[3 * H_ + tid] + bhh[3 * H_ + tid];
  #pragma unroll
  for (int r = 0; r < 8; ++r) { gi[r] = bi_; gg[r] = bg_; go[r] = bo_; }
  const float* wi_ = wih + (long)tid * IN_;
  const float* wg_ = wih + (long)(2 * H_ + tid) * IN_;
  const float* wo_ = wih + (long)(3 * H_ + tid) * IN_;
  for (int f = 0; f < IN_; ++f) {
    float a = wi_[f], gc = wg_[f], oc = wo_[f];
    #pragma unroll
    for (int r = 0; r < 8; ++r) {
      float x = fv[r][f];
      gi[r] += a * x;
      gg[r] += gc * x;
      go[r] += oc * x;
    }
  }
  #pragma unroll
  for (int r = 0; r < 8; ++r) {
    float c = sigf(gi[r]) * tanh_(gg[r]);
    hb[(long)(b0 + r) * H_ + tid] = sigf(go[r]) * tanh_(c);
  }
}

// ---------------- K6: fc head ----------------
__global__ void k_fc(const float* __restrict__ hf, const float* __restrict__ hb,
                     const float* __restrict__ fcw, const float* __restrict__ fcb,
                     float* __restrict__ out) {
  int b = blockIdx.x;
  int lane = threadIdx.x;  // 64
  float p0 = 0.f, p1 = 0.f;
  #pragma unroll
  for (int k = lane; k < 2 * H_; k += 64) {
    float v = (k < H_) ? hf[b * H_ + k] : hb[b * H_ + (k - H_)];
    p0 += v * fcw[k];
    p1 += v * fcw[2 * H_ + k];
  }
  #pragma unroll
  for (int o = 32; o; o >>= 1) {
    p0 += __shfl_down(p0, o);
    p1 += __shfl_down(p1, o);
  }
  if (lane == 0) {
    out[b * 2 + 0] = p0 + fcb[0];
    out[b * 2 + 1] = p1 + fcb[1];
  }
}

extern "C" void kernel_launch(void* const* d_in, const int* in_sizes, int n_in,
                              void* d_out, int out_size, void* d_ws, size_t ws_size,
                              hipStream_t stream) {
  const int*   x    = (const int*)  d_in[0];
  const float* emb  = (const float*)d_in[1];
  const float* tsW  = (const float*)d_in[2];
  const float* wihf = (const float*)d_in[3];
  const float* whhf = (const float*)d_in[4];
  const float* bihf = (const float*)d_in[5];
  const float* bhhf = (const float*)d_in[6];
  const float* wihb = (const float*)d_in[7];
  // d_in[8] = w_hh_b: unused (one backward step from zero state)
  const float* bihb = (const float*)d_in[9];
  const float* bhhb = (const float*)d_in[10];
  const float* fcw  = (const float*)d_in[11];
  const float* fcb  = (const float*)d_in[12];
  float* out = (float*)d_out;

  // workspace layout (243,795,968 bytes total — proven to fit)
  char* ws = (char*)d_ws;
  float* s    = (float*)(ws);                  //       2,048
  int*   wf8  = (int*)  (ws + 2048);           //     262,144 (MX fp8 W frags)
  u16*   feat = (u16*)  (ws + 264192);         //  32,768,000
  u16*   xg   = (u16*)  (ws + 33032192);       // 209,715,200
  float* hf   = (float*)(ws + 242747392);      //     524,288
  float* hb   = (float*)(ws + 243271680);      //     524,288

  k_norm   <<<dim3(512),     dim3(256), 0, stream>>>(x, s);
  k_prep_mx<<<dim3(256),     dim3(256), 0, stream>>>(whhf, wf8);
  k_feat   <<<dim3(64000),   dim3(256), 0, stream>>>(x, emb, tsW, s, feat);
  k_xg     <<<dim3(4, 400),  dim3(512), 0, stream>>>(feat, wihf, bihf, bhhf, xg);
  k_lstm_f <<<dim3(32),      dim3(512), 0, stream>>>(wf8, xg, hf);
  k_bwd    <<<dim3(64),      dim3(256), 0, stream>>>(feat, wihb, bihb, bhhb, hb);
  k_fc     <<<dim3(512),     dim3(64),  0, stream>>>(hf, hb, fcw, fcb, out);
}

// Round 7
// 729.301 us; speedup vs baseline: 1.4093x; 1.0953x over previous
//
#include <hip/hip_runtime.h>
#include <stdint.h>

// BiRNN on MI355X — round 7.
//  - r5==r6 proved LDS-W traffic and AGPR copies were never the bottleneck.
//    Closed model for r6's 4900 cy/step: VALU ~2570 (52% of 32 CUs) + MFMA
//    ~1100 (21%) + ~1200 exposed latency; phases serial at 2 waves/SIMD.
//  - This round: 16 waves x 1024 thr, 4 waves/SIMD (launch_bounds(1024,4),
//    <=128 regs/wave). Wave w owns m-tiles {w+16*tt}, tt=0..3 = i,f,g,o ->
//    4 accs, 4 cell updates/lane (was 8). W: 6 frags AGPR + 2 frags LDS.
//  - Packed f32x2 epilogue (v_pk_*), no clamps (|args|<15 by construction),
//    x16 h-scale folded into one pk_fma. B-frags as direct i32x8v LDS loads.
//  - k_norm fused into k_feat; k_bwd folded into the scan launch (blocks
//    32..95, all 96 blocks co-resident on 256 CUs).

typedef unsigned short u16;
typedef __bf16 bf16x8 __attribute__((ext_vector_type(8)));
typedef float  f32x4  __attribute__((ext_vector_type(4)));
typedef float  f32x2  __attribute__((ext_vector_type(2)));
typedef int    i32x4v __attribute__((ext_vector_type(4)));
typedef int    i32x8v __attribute__((ext_vector_type(8)));

#define B_    512
#define L_    200
#define EMB_  128
#define TDIM_ 10
#define IN_   138
#define INP_  160   // feat padded K (5 x 32)
#define H_    256
#define G4_   1024
#define T_    200
#define DS_   (1.0f/1024.0f)   // descale: (W*64)*(h*16), xg prescaled *1024
#define LOG2E 1.4426950408889634f
#define EXP2(x) __builtin_amdgcn_exp2f(x)
#define RCP(x)  __builtin_amdgcn_rcpf(x)

static __device__ __forceinline__ float bf2f(u16 u) {
  union { uint32_t i; float f; } v; v.i = ((uint32_t)u) << 16; return v.f;
}
static __device__ __forceinline__ u16 f2bf(float f) {
  __bf16 h = (__bf16)f; return __builtin_bit_cast(u16, h);
}
static __device__ __forceinline__ float bflo(uint32_t u) {
  return __builtin_bit_cast(float, (uint32_t)(u << 16));
}
static __device__ __forceinline__ float bfhi(uint32_t u) {
  return __builtin_bit_cast(float, (uint32_t)(u & 0xffff0000u));
}
static __device__ __forceinline__ float sigf(float x) {
  return RCP(1.0f + EXP2(-x * LOG2E));
}
static __device__ __forceinline__ float tanh_(float x) {
  x = fminf(fmaxf(x, -15.f), 15.f);
  float e = EXP2(2.0f * LOG2E * x);
  return (e - 1.0f) * RCP(e + 1.0f);
}
static __device__ __forceinline__ f32x4 mfma16(bf16x8 a, bf16x8 b, f32x4 c) {
  return __builtin_amdgcn_mfma_f32_16x16x32_bf16(a, b, c, 0, 0, 0);
}
static __device__ __forceinline__ f32x4 vzero4() {
  f32x4 v; v[0] = 0.f; v[1] = 0.f; v[2] = 0.f; v[3] = 0.f; return v;
}

// ---------------- K0b: W_hh fp32 -> K=128 MX A-frags, fp8 e4m3 *64 ---------
// UNCHANGED from r5/r6 (layout validated). frag fs = w8*16 + tt8*2 + kp2,
// m-tile M = w8 + 8*tt8; lane(q,mm): A[g=(M)*16+mm][k=kp2*128+q*32+d*4+byte]
__global__ void k_prep_mx(const float* __restrict__ whh, int* __restrict__ wf8) {
  int idx = blockIdx.x * blockDim.x + threadIdx.x;  // < 65536 dwords
  int d = idx & 7;
  int lane = (idx >> 3) & 63;
  int fs = idx >> 9;
  int kp2 = fs & 1, tt = (fs >> 1) & 7, w = fs >> 4;
  int mm = lane & 15, q = lane >> 4;
  int g = (w + 8 * tt) * 16 + mm;
  int k = kp2 * 128 + q * 32 + d * 4;
  const float* src = whh + g * 256 + k;
  int v = __builtin_amdgcn_cvt_pk_fp8_f32(src[0] * 64.f, src[1] * 64.f, 0, false);
  v     = __builtin_amdgcn_cvt_pk_fp8_f32(src[2] * 64.f, src[3] * 64.f, v, true);
  wf8[idx] = v;
}

// ---------------- K2: norm + features fused (512 blocks, one per batch) -----
__global__ __launch_bounds__(256) void k_feat(
    const int* __restrict__ x, const float* __restrict__ emb,
    const float* __restrict__ tsW, u16* __restrict__ feat) {
  __shared__ float sh_t[224];
  __shared__ int   sh_id[224];
  __shared__ float sh_s[4];
  const int b = blockIdx.x, tid = threadIdx.x;
  float v = 0.f;
  if (tid < L_) {
    int2 p = *(const int2*)&x[(b * L_ + tid) * 2];
    float t = (float)p.x;
    sh_t[tid] = t;
    sh_id[tid] = p.y;
    v = t * t;
  }
  #pragma unroll
  for (int o = 32; o; o >>= 1) v += __shfl_down(v, o);
  if ((tid & 63) == 0) sh_s[tid >> 6] = v;
  __syncthreads();
  const float sq = sqrtf(sh_s[0] + sh_s[1] + sh_s[2] + sh_s[3]);
  for (int i = tid; i < L_ * INP_; i += 256) {
    int l = i / INP_, c = i - l * INP_;
    float v2 = 0.f;
    if (c < TDIM_) {
      float wd = tsW[c];
      float den = fmaxf(fabsf(wd) * sq, 1e-12f);
      v2 = sh_t[l] * wd * RCP(den);
    } else if (c < IN_) {
      int id = sh_id[l];
      float e = emb[(long)(id < 0 ? 0 : id) * EMB_ + (c - TDIM_)];
      v2 = (id >= 0) ? e : 0.f;
    }
    feat[(long)b * (L_ * INP_) + i] = f2bf(v2);
  }
}

// ---------------- K3: xg = (feat @ W_ih^T + b_ih + b_hh) * 1024, bf16 -------
// UNCHANGED from r6 (validated).
__global__ __launch_bounds__(512, 2) void k_xg(
    const u16* __restrict__ feat, const float* __restrict__ wih,
    const float* __restrict__ bih, const float* __restrict__ bhh,
    u16* __restrict__ xg) {
  __shared__ u16 Bs[256 * 176];
  const int nt = blockIdx.x;   // 0..3
  const int mt = blockIdx.y;   // 0..399
  const int tid = threadIdx.x;
  const int w = tid >> 6, lane = tid & 63;
  const int q = lane >> 4, nm = lane & 15;
  for (int i2 = tid; i2 < 256 * 88; i2 += 512) {
    int gl = i2 / 88, f2 = (i2 % 88) * 2;
    int pk = 0;
    if (f2 < IN_) {
      float2 v = *(const float2*)(wih + (long)(nt * 256 + gl) * IN_ + f2);
      pk = (int)f2bf(v.x) | ((int)f2bf(v.y) << 16);
    }
    *(int*)&Bs[gl * 176 + f2] = pk;
  }
  float bias[16];
  #pragma unroll
  for (int nu = 0; nu < 16; ++nu) {
    int g = nt * 256 + nu * 16 + nm;
    bias[nu] = bih[g] + bhh[g];
  }
  __syncthreads();
  f32x4 acc[2][16];
  #pragma unroll
  for (int m = 0; m < 2; ++m)
    #pragma unroll
    for (int nu = 0; nu < 16; ++nu) acc[m][nu] = vzero4();
  const u16* arow = feat + (long)(mt * 256 + w * 32) * INP_;
  #pragma unroll
  for (int kp = 0; kp < 5; ++kp) {
    bf16x8 a0 = *(const bf16x8*)(arow + (nm * INP_ + kp * 32 + q * 8));
    bf16x8 a1 = *(const bf16x8*)(arow + ((16 + nm) * INP_ + kp * 32 + q * 8));
    #pragma unroll
    for (int nu = 0; nu < 16; ++nu) {
      bf16x8 bb = *(const bf16x8*)&Bs[(nu * 16 + nm) * 176 + kp * 32 + q * 8];
      acc[0][nu] = mfma16(a0, bb, acc[0][nu]);
      acc[1][nu] = mfma16(a1, bb, acc[1][nu]);
    }
  }
  u16* Os = Bs;
  #pragma unroll
  for (int p = 0; p < 2; ++p) {
    __syncthreads();
    if ((w >> 2) == p) {
      #pragma unroll
      for (int nu = 0; nu < 16; ++nu)
        #pragma unroll
        for (int m = 0; m < 2; ++m)
          #pragma unroll
          for (int r = 0; r < 4; ++r) {
            int row = (w & 3) * 32 + m * 16 + 4 * q + r;
            Os[row * 264 + nu * 16 + nm] = f2bf((acc[m][nu][r] + bias[nu]) * 1024.f);
          }
    }
    __syncthreads();
    #pragma unroll
    for (int it = 0; it < 8; ++it) {
      int flat = it * 512 + tid;
      int row = flat >> 5, c = flat & 31;
      uint4 v = *(const uint4*)&Os[row * 264 + c * 8];
      *(uint4*)&xg[(long)(mt * 256 + p * 128 + row) * G4_ + nt * 256 + c * 8] = v;
    }
  }
}

// ---------------- K4: scan (blocks 0..31) + folded bwd (blocks 32..95) ------
#define F8MA(accv, Aa, Bv) \
  asm volatile("v_mfma_f32_16x16x128_f8f6f4 %0, %1, %2, %0" \
               : "+v"(accv) : "a"(Aa), "v"(Bv));
#define F8MV(accv, Av, Bv) \
  asm volatile("v_mfma_f32_16x16x128_f8f6f4 %0, %1, %2, %0" \
               : "+v"(accv) : "v"(Av), "v"(Bv));
#define AINIT(i) \
  f32x4 acc##i; acc##i[0] = bflo(pf##i.x); acc##i[1] = bfhi(pf##i.x); \
  acc##i[2] = bflo(pf##i.y); acc##i[3] = bfhi(pf##i.y);
#define PFL(i, ptr) pf##i = *(const uint2*)((ptr) + (16 * (w + 16 * (i)) + 4 * q));
// packed-pair cell update; acc0=i acc1=f acc2=g acc3=o rows {2P, 2P+1}
#define EPIPAIR(P, cs2, hv2) f32x2 hv2; { \
  f32x2 ai = {acc0[2*(P)], acc0[2*(P)+1]}; \
  f32x2 af = {acc1[2*(P)], acc1[2*(P)+1]}; \
  f32x2 ag = {acc2[2*(P)], acc2[2*(P)+1]}; \
  f32x2 ao = {acc3[2*(P)], acc3[2*(P)+1]}; \
  f32x2 xi = ai * c_sig, xf = af * c_sig, xo = ao * c_sig, xgv = ag * c_tg; \
  f32x2 ei, ef, eo, eg, ec; \
  ei[0] = EXP2(xi[0]); ei[1] = EXP2(xi[1]); \
  ef[0] = EXP2(xf[0]); ef[1] = EXP2(xf[1]); \
  eo[0] = EXP2(xo[0]); eo[1] = EXP2(xo[1]); \
  eg[0] = EXP2(xgv[0]); eg[1] = EXP2(xgv[1]); \
  f32x2 t1 = ef + 1.f; \
  f32x2 r1; r1[0] = RCP(t1[0]); r1[1] = RCP(t1[1]); \
  f32x2 t2 = (ei + 1.f) * (eg + 1.f); \
  f32x2 r2; r2[0] = RCP(t2[0]); r2[1] = RCP(t2[1]); \
  f32x2 c = cs2 * r1 + (eg - 1.f) * r2; \
  cs2 = c; \
  f32x2 xc = c * c_tc; \
  ec[0] = EXP2(xc[0]); ec[1] = EXP2(xc[1]); \
  f32x2 t3 = (eo + 1.f) * (ec + 1.f); \
  f32x2 r3; r3[0] = RCP(t3[0]); r3[1] = RCP(t3[1]); \
  hv2 = (ec * 16.f - 16.f) * r3; }   /* = h*16 for fp8 store */

#define FSOLD(M, kp2) (((M) & 7) * 16 + ((M) >> 3) * 2 + (kp2))
#define WLOAD(M, kp2) (*(const i32x8v*)(wf8 + ((long)(FSOLD(M, kp2)) * 64 + lane) * 8))

__global__ __launch_bounds__(1024, 4) void k_lstm_f(
    const int* __restrict__ wf8, const u16* __restrict__ xg,
    float* __restrict__ hf,
    const u16* __restrict__ feat, const float* __restrict__ wihb,
    const float* __restrict__ bihb, const float* __restrict__ bhhb,
    float* __restrict__ hb) {
  __shared__ i32x8v ldsW[32 * 64];   // 65536 B: tt=3 (o-gate) frags
  __shared__ int hls[2][16 * 68];    // 8704 B: fp8 h, stride 272 B, dbuf

  if (blockIdx.x >= 32) {
    // ---- folded one-step backward LSTM (c0=0 -> forget gate dead) ----
    const int b0 = (blockIdx.x - 32) * 8;
    const int tid = threadIdx.x;   // 0..1023
    float* fv = (float*)hls;       // 1104 floats needed, 2176 available
    for (int i = tid; i < 8 * IN_; i += 1024) {
      int r = i / IN_, c = i - r * IN_;
      fv[r * IN_ + c] = bf2f(feat[((long)(b0 + r) * L_ + (L_ - 1)) * INP_ + c]);
    }
    __syncthreads();
    const int col = tid & 255, rq = tid >> 8;   // rows rq*2, rq*2+1
    float gi0 = bihb[col] + bhhb[col];
    float gg0 = bihb[512 + col] + bhhb[512 + col];
    float go0 = bihb[768 + col] + bhhb[768 + col];
    float gi1 = gi0, gg1 = gg0, go1 = go0;
    const float* wi_ = wihb + (long)col * IN_;
    const float* wg_ = wihb + (long)(512 + col) * IN_;
    const float* wo_ = wihb + (long)(768 + col) * IN_;
    const float* f0 = fv + (rq * 2) * IN_;
    const float* f1 = fv + (rq * 2 + 1) * IN_;
    for (int f = 0; f < IN_; ++f) {
      float a = wi_[f], g = wg_[f], o = wo_[f];
      float x0 = f0[f], x1 = f1[f];
      gi0 += a * x0; gi1 += a * x1;
      gg0 += g * x0; gg1 += g * x1;
      go0 += o * x0; go1 += o * x1;
    }
    float c0 = sigf(gi0) * tanh_(gg0);
    float c1 = sigf(gi1) * tanh_(gg1);
    hb[(long)(b0 + rq * 2) * H_ + col]     = sigf(go0) * tanh_(c0);
    hb[(long)(b0 + rq * 2 + 1) * H_ + col] = sigf(go1) * tanh_(c1);
    return;
  }

  // ---- forward scan: 16 waves, wave w owns m-tiles {w+16*tt}, tt=i,f,g,o --
  const int tid = threadIdx.x;
  const int w = tid >> 6;          // 0..15
  const int lane = tid & 63;
  const int q = lane >> 4;
  const int nn = lane & 15;
  const int b = blockIdx.x * 16 + nn;
  const float c_sig = -DS_ * LOG2E;
  const float c_tg  = 2.f * DS_ * LOG2E;
  const float c_tc  = 2.f * LOG2E;

  // W frags: tt=0,1,2 (i,f,g) -> AGPR via "a" uses; tt=3 (o) -> LDS
  i32x8v A00 = WLOAD(w, 0),      A01 = WLOAD(w, 1);
  i32x8v A10 = WLOAD(w + 16, 0), A11 = WLOAD(w + 16, 1);
  i32x8v A20 = WLOAD(w + 32, 0), A21 = WLOAD(w + 32, 1);
  ldsW[(w * 2 + 0) * 64 + lane] = WLOAD(w + 48, 0);
  ldsW[(w * 2 + 1) * 64 + lane] = WLOAD(w + 48, 1);
  for (int i = tid; i < 16 * 68; i += 1024) hls[0][i] = 0;

  const u16* xgb = xg + (long)b * (L_ * G4_);
  uint2 pf0, pf1, pf2, pf3;
  PFL(0, xgb) PFL(1, xgb) PFL(2, xgb) PFL(3, xgb)
  f32x2 cs0; cs0[0] = 0.f; cs0[1] = 0.f;
  f32x2 cs1; cs1[0] = 0.f; cs1[1] = 0.f;
  __syncthreads();

  #pragma unroll 1
  for (int t = 0; t < T_; ++t) {
    const int* hr = hls[t & 1];
    i32x8v B0 = *(const i32x8v*)&hr[nn * 68 + q * 8];         // k 0..127
    i32x8v B1 = *(const i32x8v*)&hr[nn * 68 + 32 + q * 8];    // k 128..255
    i32x8v L0 = ldsW[(w * 2 + 0) * 64 + lane];
    i32x8v L1 = ldsW[(w * 2 + 1) * 64 + lane];
    AINIT(0) AINIT(1) AINIT(2) AINIT(3)
    {  // next step's xg prefetch; barrier is lgkm-only so it stays in flight
      const u16* xn = xgb + (long)(t + 1 < T_ ? t + 1 : t) * G4_;
      PFL(0, xn) PFL(1, xn) PFL(2, xn) PFL(3, xn)
    }
    F8MA(acc0, A00, B0) F8MA(acc1, A10, B0) F8MA(acc2, A20, B0) F8MV(acc3, L0, B0)
    F8MA(acc0, A01, B1) F8MA(acc1, A11, B1) F8MA(acc2, A21, B1) F8MV(acc3, L1, B1)
    asm volatile("s_nop 7\n\ts_nop 7"
                 : "+v"(acc0), "+v"(acc1), "+v"(acc2), "+v"(acc3));
    int* hw = hls[1 - (t & 1)];
    EPIPAIR(0, cs0, hv0)   // rows 0,1
    EPIPAIR(1, cs1, hv1)   // rows 2,3
    int pk = __builtin_amdgcn_cvt_pk_fp8_f32(hv0[0], hv0[1], 0, false);
    pk     = __builtin_amdgcn_cvt_pk_fp8_f32(hv1[0], hv1[1], pk, true);
    hw[nn * 68 + 4 * w + q] = pk;
    if (t == T_ - 1) {
      f32x4 ov;
      ov[0] = hv0[0] * 0.0625f; ov[1] = hv0[1] * 0.0625f;
      ov[2] = hv1[0] * 0.0625f; ov[3] = hv1[1] * 0.0625f;
      *(f32x4*)&hf[(long)b * H_ + 16 * w + 4 * q] = ov;
    }
    // raw barrier: wait DS only (lgkmcnt(0)); vmcnt prefetch NOT drained.
    __asm__ volatile("" ::: "memory");
    __builtin_amdgcn_s_waitcnt(0xc07f);
    __builtin_amdgcn_s_barrier();
    __asm__ volatile("" ::: "memory");
  }
}

// ---------------- K6: fc head ----------------
__global__ void k_fc(const float* __restrict__ hf, const float* __restrict__ hb,
                     const float* __restrict__ fcw, const float* __restrict__ fcb,
                     float* __restrict__ out) {
  int b = blockIdx.x;
  int lane = threadIdx.x;  // 64
  float p0 = 0.f, p1 = 0.f;
  #pragma unroll
  for (int k = lane; k < 2 * H_; k += 64) {
    float v = (k < H_) ? hf[b * H_ + k] : hb[b * H_ + (k - H_)];
    p0 += v * fcw[k];
    p1 += v * fcw[2 * H_ + k];
  }
  #pragma unroll
  for (int o = 32; o; o >>= 1) {
    p0 += __shfl_down(p0, o);
    p1 += __shfl_down(p1, o);
  }
  if (lane == 0) {
    out[b * 2 + 0] = p0 + fcb[0];
    out[b * 2 + 1] = p1 + fcb[1];
  }
}

extern "C" void kernel_launch(void* const* d_in, const int* in_sizes, int n_in,
                              void* d_out, int out_size, void* d_ws, size_t ws_size,
                              hipStream_t stream) {
  const int*   x    = (const int*)  d_in[0];
  const float* emb  = (const float*)d_in[1];
  const float* tsW  = (const float*)d_in[2];
  const float* wihf = (const float*)d_in[3];
  const float* whhf = (const float*)d_in[4];
  const float* bihf = (const float*)d_in[5];
  const float* bhhf = (const float*)d_in[6];
  const float* wihb = (const float*)d_in[7];
  // d_in[8] = w_hh_b: unused (one backward step from zero state)
  const float* bihb = (const float*)d_in[9];
  const float* bhhb = (const float*)d_in[10];
  const float* fcw  = (const float*)d_in[11];
  const float* fcb  = (const float*)d_in[12];
  float* out = (float*)d_out;

  // workspace layout (243,795,968 bytes total — proven to fit)
  char* ws = (char*)d_ws;
  int*   wf8  = (int*)  (ws + 2048);           //     262,144 (MX fp8 W frags)
  u16*   feat = (u16*)  (ws + 264192);         //  32,768,000
  u16*   xg   = (u16*)  (ws + 33032192);       // 209,715,200
  float* hf   = (float*)(ws + 242747392);      //     524,288
  float* hb   = (float*)(ws + 243271680);      //     524,288

  k_prep_mx<<<dim3(256),    dim3(256),  0, stream>>>(whhf, wf8);
  k_feat   <<<dim3(512),    dim3(256),  0, stream>>>(x, emb, tsW, feat);
  k_xg     <<<dim3(4, 400), dim3(512),  0, stream>>>(feat, wihf, bihf, bhhf, xg);
  k_lstm_f <<<dim3(96),     dim3(1024), 0, stream>>>(wf8, xg, hf,
                                                     feat, wihb, bihb, bhhb, hb);
  k_fc     <<<dim3(512),    dim3(64),   0, stream>>>(hf, hb, fcw, fcb, out);
}